// Round 28
// baseline (1748.087 us; speedup 1.0000x reference)
//
#include <hip/hip_runtime.h>
#include <math.h>

#define B_   16
#define L_   1024
#define C_   64
#define D_   512
#define DFF_ 2048
#define TOPK_ 20

typedef float f4 __attribute__((ext_vector_type(4)));
typedef float f32x4 __attribute__((ext_vector_type(4)));
typedef short bf16x8 __attribute__((ext_vector_type(8)));
typedef unsigned short u16x8 __attribute__((ext_vector_type(8)));

__device__ __forceinline__ unsigned short f2bf(float f) {
    union { float f; unsigned u; } a; a.f = f;
    unsigned r = a.u + 0x7fff + ((a.u >> 16) & 1);
    return (unsigned short)(r >> 16);
}
__device__ __forceinline__ float bf2f(unsigned short h) {
    union { unsigned u; float f; } a; a.u = ((unsigned)h) << 16;
    return a.f;
}

// Fast exact-GELU: erf via Abramowitz-Stegun 7.1.26 (|err|<=1.5e-7, far below
// the bf16 output quantum ~4e-3 rel) with native rcp/exp.
__device__ __forceinline__ float gelu_fast(float c) {
    float z  = c * 0.70710678118654752f;
    float az = fabsf(z);
    float t  = __builtin_amdgcn_rcpf(fmaf(0.3275911f, az, 1.0f));
    float p  = fmaf(fmaf(fmaf(fmaf(1.061405429f, t, -1.453152027f), t,
                              1.421413741f), t, -0.284496736f), t, 0.254829592f) * t;
    float e  = __expf(-z * z);
    float ea = fmaf(-p, e, 1.0f);
    float er = copysignf(ea, z);
    return 0.5f * c * (1.0f + er);
}

__device__ __forceinline__ void gld16(const void* g, void* l) {
    __builtin_amdgcn_global_load_lds(
        (const __attribute__((address_space(1))) unsigned int*)g,
        (__attribute__((address_space(3))) unsigned int*)l, 16, 0, 0);
}

// LDS swizzle (all MFMA kernels): permute 16B source slot at staging
// (kq ^= lane row bits) and XOR the read slot identically -> bank-conflict
// free (verified: SQ_LDS_BANK_CONFLICT 4.19M -> 0). Bit-identical data.

// ---------------------------------------------------------------------------
// bf16 MFMA GEMM: C[M,N] = op(A[M,K] @ B[K,N] + bias). BK=64.
// ---------------------------------------------------------------------------
__global__ __launch_bounds__(256)
void gemm_bf16(const unsigned short* __restrict__ A, const unsigned short* __restrict__ Bt,
               float* __restrict__ Cf, unsigned short* __restrict__ Cb,
               unsigned short* __restrict__ Cl,
               const float* __restrict__ bias, int M, int N, int K, int flags, int nx)
{
    __shared__ unsigned short As0[128 * 32], As1[128 * 32];
    __shared__ unsigned short Bs0[128 * 32], Bs1[128 * 32];
    const int tid = threadIdx.x;
    const int wave = tid >> 6, lane = tid & 63;

    int total = gridDim.x;
    int h = blockIdx.x;
    int lidx = h;
    if ((total & 7) == 0) {
        int q = total >> 3;
        lidx = (h & 7) * q + (h >> 3);
    }
    const int bm = (lidx / nx) * 128, bn = (lidx % nx) * 128;
    const int wm = (wave >> 1) << 6, wn = (wave & 1) << 6;

    const int r0 = (wave << 5) + (lane >> 2);
    const int kq = (((lane & 3) ^ ((lane >> 3) & 3)) << 3);   // swizzled source slot
    const unsigned short* Ap0 = A + (size_t)(bm + r0) * K + kq;
    const unsigned short* Ap1 = Ap0 + (size_t)16 * K;
    const unsigned short* Bp0 = Bt + (size_t)(bn + r0) * K + kq;
    const unsigned short* Bp1 = Bp0 + (size_t)16 * K;
    const int wo0 = (wave << 5) * 32, wo1 = ((wave << 5) + 16) * 32;

    const int la = lane & 15, h4 = lane >> 4;
    const int sw = (la >> 1) & 3;                              // read-side slot XOR
    f32x4 acc[4][4] = {};

    for (int k0 = 0; k0 < K; k0 += 64) {
        gld16(Ap0 + k0, &As0[wo0]);      gld16(Ap1 + k0, &As0[wo1]);
        gld16(Bp0 + k0, &Bs0[wo0]);      gld16(Bp1 + k0, &Bs0[wo1]);
        gld16(Ap0 + k0 + 32, &As1[wo0]); gld16(Ap1 + k0 + 32, &As1[wo1]);
        gld16(Bp0 + k0 + 32, &Bs1[wo0]); gld16(Bp1 + k0 + 32, &Bs1[wo1]);
        __syncthreads();
        bf16x8 a[4], b[4];
#pragma unroll
        for (int i = 0; i < 4; ++i) {
            a[i] = *(const bf16x8*)&As0[(wm + i * 16 + la) * 32 + ((h4 ^ sw) << 3)];
            b[i] = *(const bf16x8*)&Bs0[(wn + i * 16 + la) * 32 + ((h4 ^ sw) << 3)];
        }
#pragma unroll
        for (int mi = 0; mi < 4; ++mi)
#pragma unroll
            for (int ni = 0; ni < 4; ++ni)
                acc[mi][ni] = __builtin_amdgcn_mfma_f32_16x16x32_bf16(a[mi], b[ni], acc[mi][ni], 0, 0, 0);
#pragma unroll
        for (int i = 0; i < 4; ++i) {
            a[i] = *(const bf16x8*)&As1[(wm + i * 16 + la) * 32 + ((h4 ^ sw) << 3)];
            b[i] = *(const bf16x8*)&Bs1[(wn + i * 16 + la) * 32 + ((h4 ^ sw) << 3)];
        }
#pragma unroll
        for (int mi = 0; mi < 4; ++mi)
#pragma unroll
            for (int ni = 0; ni < 4; ++ni)
                acc[mi][ni] = __builtin_amdgcn_mfma_f32_16x16x32_bf16(a[mi], b[ni], acc[mi][ni], 0, 0, 0);
        __syncthreads();
    }

#pragma unroll
    for (int mi = 0; mi < 4; ++mi) {
#pragma unroll
        for (int r = 0; r < 4; ++r) {
            int m = bm + wm + mi * 16 + h4 * 4 + r;
#pragma unroll
            for (int ni = 0; ni < 4; ++ni) {
                int n = bn + wn + ni * 16 + la;
                float c = acc[mi][ni][r];
                if (bias) c += bias[n];
                if (flags & 2) c = gelu_fast(c);
                size_t o = (size_t)m * N + n;
                if (Cf) { if (flags & 1) Cf[o] += c; else Cf[o] = c; }
                if (Cb) {
                    unsigned short hb = f2bf(c);
                    Cb[o] = hb;
                    if (Cl) Cl[o] = f2bf(c - bf2f(hb));
                }
            }
        }
    }
}

// ---------------------------------------------------------------------------
// FF1 GEMM: 256x256 tile, 512 threads (8 waves, 2Mx4N), BK=64, double-buffered
// LDS (128KB) with next-K-step prefetch. 1 block/CU -> dbuf costs nothing.
// GELU epilogue, bf16-out only. Bit-identical K order.
// ---------------------------------------------------------------------------
__global__ __launch_bounds__(512)
void gemm256_gelu(const unsigned short* __restrict__ A, const unsigned short* __restrict__ Bt,
                  unsigned short* __restrict__ Cb, int M, int N, int K, int nx)
{
    __shared__ unsigned short As[2][16384];   // [buf][half*8192 + row*32 + slot]
    __shared__ unsigned short Bs[2][16384];
    const int tid = threadIdx.x;
    const int wave = tid >> 6, lane = tid & 63;

    int total = gridDim.x;
    int h = blockIdx.x;
    int lidx = h;
    if ((total & 7) == 0) {
        int q = total >> 3;
        lidx = (h & 7) * q + (h >> 3);
    }
    const int bm = (lidx / nx) * 256, bn = (lidx % nx) * 256;
    const int wm = (wave >> 2) << 7, wn = (wave & 3) << 6;

    const int r0 = (wave << 5) + (lane >> 2);
    const int kq = (((lane & 3) ^ ((lane >> 3) & 3)) << 3);   // swizzled source slot
    const unsigned short* Ap0 = A + (size_t)(bm + r0) * K + kq;
    const unsigned short* Ap1 = Ap0 + (size_t)16 * K;
    const unsigned short* Bp0 = Bt + (size_t)(bn + r0) * K + kq;
    const unsigned short* Bp1 = Bp0 + (size_t)16 * K;
    const int wo0 = (wave << 5) * 32, wo1 = ((wave << 5) + 16) * 32;

    const int la = lane & 15, h4 = lane >> 4;
    const int sw = (la >> 1) & 3;
    f32x4 acc[8][4] = {};

    // prologue: stage K-step 0 into buffer 0
    gld16(Ap0, &As[0][wo0]);             gld16(Ap1, &As[0][wo1]);
    gld16(Bp0, &Bs[0][wo0]);             gld16(Bp1, &Bs[0][wo1]);
    gld16(Ap0 + 32, &As[0][8192 + wo0]); gld16(Ap1 + 32, &As[0][8192 + wo1]);
    gld16(Bp0 + 32, &Bs[0][8192 + wo0]); gld16(Bp1 + 32, &Bs[0][8192 + wo1]);
    __syncthreads();

    const int nt = K >> 6;
    for (int t = 0; t < nt; ++t) {
        if (t + 1 < nt) {   // prefetch next K-step into the other buffer
            const int k0 = (t + 1) << 6;
            const int nb2 = (t + 1) & 1;
            gld16(Ap0 + k0, &As[nb2][wo0]);             gld16(Ap1 + k0, &As[nb2][wo1]);
            gld16(Bp0 + k0, &Bs[nb2][wo0]);             gld16(Bp1 + k0, &Bs[nb2][wo1]);
            gld16(Ap0 + k0 + 32, &As[nb2][8192 + wo0]); gld16(Ap1 + k0 + 32, &As[nb2][8192 + wo1]);
            gld16(Bp0 + k0 + 32, &Bs[nb2][8192 + wo0]); gld16(Bp1 + k0 + 32, &Bs[nb2][8192 + wo1]);
        }
        const int cb = t & 1;
#pragma unroll
        for (int hh = 0; hh < 2; ++hh) {
            const int hb = hh << 13;
            bf16x8 a[8], b[4];
#pragma unroll
            for (int i = 0; i < 8; ++i)
                a[i] = *(const bf16x8*)&As[cb][hb + (wm + i * 16 + la) * 32 + ((h4 ^ sw) << 3)];
#pragma unroll
            for (int i = 0; i < 4; ++i)
                b[i] = *(const bf16x8*)&Bs[cb][hb + (wn + i * 16 + la) * 32 + ((h4 ^ sw) << 3)];
#pragma unroll
            for (int mi = 0; mi < 8; ++mi)
#pragma unroll
                for (int ni = 0; ni < 4; ++ni)
                    acc[mi][ni] = __builtin_amdgcn_mfma_f32_16x16x32_bf16(a[mi], b[ni], acc[mi][ni], 0, 0, 0);
        }
        __syncthreads();   // drains prefetch (had full compute phase to land)
    }

#pragma unroll
    for (int mi = 0; mi < 8; ++mi)
#pragma unroll
        for (int r = 0; r < 4; ++r) {
            int m = bm + wm + mi * 16 + h4 * 4 + r;
#pragma unroll
            for (int ni = 0; ni < 4; ++ni) {
                int n = bn + wn + ni * 16 + la;
                Cb[(size_t)m * N + n] = f2bf(gelu_fast(acc[mi][ni][r]));
            }
        }
}

// ---------------------------------------------------------------------------
// FF2 GEMM: 256x256 tile x split-K/2, 512 threads, BK=64, dbuf prefetch.
// Grid = 64 M x 2 N x 2 K-halves = 256 = one full-GPU round (fixes r25's
// half-idle/32-MFMA-step failure: full 64 MFMA/step geometry kept, K split
// across blocks instead of narrowing N). Epilogue: atomicAdd into the f32
// residual -- each address touched by exactly 2 blocks (no hot contention);
// f32 regrouping/order perturbation ~1e-6 (accepted class, cf. corr G).
// ---------------------------------------------------------------------------
__global__ __launch_bounds__(512)
void gemm256_ffr(const unsigned short* __restrict__ A, const unsigned short* __restrict__ Bt,
                 float* __restrict__ Cf, int M, int N, int K)
{
    __shared__ unsigned short As[2][16384];
    __shared__ unsigned short Bs[2][16384];
    const int tid = threadIdx.x;
    const int wave = tid >> 6, lane = tid & 63;

    int total = gridDim.x;
    int h = blockIdx.x;
    int lidx = h;
    if ((total & 7) == 0) {
        int q = total >> 3;
        lidx = (h & 7) * q + (h >> 3);
    }
    const int kh = lidx & 1;
    const int rem = lidx >> 1;
    const int bn = (rem & 1) * 256;
    const int bm = (rem >> 1) * 256;
    const int kbase = kh * (K >> 1);

    const int wm = (wave >> 2) << 7, wn = (wave & 3) << 6;
    const int r0 = (wave << 5) + (lane >> 2);
    const int kq = (((lane & 3) ^ ((lane >> 3) & 3)) << 3);   // swizzled source slot
    const unsigned short* Ap0 = A + (size_t)(bm + r0) * K + kbase + kq;
    const unsigned short* Ap1 = Ap0 + (size_t)16 * K;
    const unsigned short* Bp0 = Bt + (size_t)(bn + r0) * K + kbase + kq;
    const unsigned short* Bp1 = Bp0 + (size_t)16 * K;
    const int wo0 = (wave << 5) * 32, wo1 = ((wave << 5) + 16) * 32;

    const int la = lane & 15, h4 = lane >> 4;
    const int sw = (la >> 1) & 3;
    f32x4 acc[8][4] = {};

    // prologue: stage K-step 0 into buffer 0
    gld16(Ap0, &As[0][wo0]);             gld16(Ap1, &As[0][wo1]);
    gld16(Bp0, &Bs[0][wo0]);             gld16(Bp1, &Bs[0][wo1]);
    gld16(Ap0 + 32, &As[0][8192 + wo0]); gld16(Ap1 + 32, &As[0][8192 + wo1]);
    gld16(Bp0 + 32, &Bs[0][8192 + wo0]); gld16(Bp1 + 32, &Bs[0][8192 + wo1]);
    __syncthreads();

    const int nt = K >> 7;   // (K/2)/64 steps
    for (int t = 0; t < nt; ++t) {
        if (t + 1 < nt) {
            const int k0 = (t + 1) << 6;
            const int nb2 = (t + 1) & 1;
            gld16(Ap0 + k0, &As[nb2][wo0]);             gld16(Ap1 + k0, &As[nb2][wo1]);
            gld16(Bp0 + k0, &Bs[nb2][wo0]);             gld16(Bp1 + k0, &Bs[nb2][wo1]);
            gld16(Ap0 + k0 + 32, &As[nb2][8192 + wo0]); gld16(Ap1 + k0 + 32, &As[nb2][8192 + wo1]);
            gld16(Bp0 + k0 + 32, &Bs[nb2][8192 + wo0]); gld16(Bp1 + k0 + 32, &Bs[nb2][8192 + wo1]);
        }
        const int cb = t & 1;
#pragma unroll
        for (int hh = 0; hh < 2; ++hh) {
            const int hb = hh << 13;
            bf16x8 a[8], b[4];
#pragma unroll
            for (int i = 0; i < 8; ++i)
                a[i] = *(const bf16x8*)&As[cb][hb + (wm + i * 16 + la) * 32 + ((h4 ^ sw) << 3)];
#pragma unroll
            for (int i = 0; i < 4; ++i)
                b[i] = *(const bf16x8*)&Bs[cb][hb + (wn + i * 16 + la) * 32 + ((h4 ^ sw) << 3)];
#pragma unroll
            for (int mi = 0; mi < 8; ++mi)
#pragma unroll
                for (int ni = 0; ni < 4; ++ni)
                    acc[mi][ni] = __builtin_amdgcn_mfma_f32_16x16x32_bf16(a[mi], b[ni], acc[mi][ni], 0, 0, 0);
        }
        __syncthreads();
    }

#pragma unroll
    for (int mi = 0; mi < 8; ++mi)
#pragma unroll
        for (int r = 0; r < 4; ++r) {
            int m = bm + wm + mi * 16 + h4 * 4 + r;
#pragma unroll
            for (int ni = 0; ni < 4; ++ni) {
                int n = bn + wn + ni * 16 + la;
                atomicAdd(&Cf[(size_t)m * N + n], acc[mi][ni][r]);
            }
        }
}

// ---------------------------------------------------------------------------
// Merged QKV projection GEMM: N = 1536 (Q|K|V) or 1024 (K|V). BK=64.
// Gz: optional 16384-float buffer zeroed by the first 64 raw blocks.
// ---------------------------------------------------------------------------
__global__ __launch_bounds__(256)
void gemm_split(const unsigned short* __restrict__ A, const unsigned short* __restrict__ Bt,
                unsigned short* __restrict__ o0h, unsigned short* __restrict__ o0l, const float* __restrict__ b0,
                unsigned short* __restrict__ o1h, unsigned short* __restrict__ o1l, const float* __restrict__ b1,
                unsigned short* __restrict__ o2h, unsigned short* __restrict__ o2l, const float* __restrict__ b2,
                float* __restrict__ Gz, int M, int N, int K, int nx)
{
    __shared__ unsigned short As0[128 * 32], As1[128 * 32];
    __shared__ unsigned short Bs0[128 * 32], Bs1[128 * 32];
    const int tid = threadIdx.x;
    const int wave = tid >> 6, lane = tid & 63;

    int total = gridDim.x;
    int h = blockIdx.x;
    if (Gz && h < 64) Gz[h * 256 + tid] = 0.f;
    int lidx = h;
    if ((total & 7) == 0) {
        int q = total >> 3;
        lidx = (h & 7) * q + (h >> 3);
    }
    const int bm = (lidx / nx) * 128, bn = (lidx % nx) * 128;
    const int wm = (wave >> 1) << 6, wn = (wave & 1) << 6;

    const int sel = bn >> 9;
    unsigned short* oh = sel == 0 ? o0h : (sel == 1 ? o1h : o2h);
    unsigned short* ol = sel == 0 ? o0l : (sel == 1 ? o1l : o2l);
    const float* bias  = sel == 0 ? b0  : (sel == 1 ? b1  : b2);
    const int nb = bn & 511;

    const int r0 = (wave << 5) + (lane >> 2);
    const int kq = (((lane & 3) ^ ((lane >> 3) & 3)) << 3);   // swizzled source slot
    const unsigned short* Ap0 = A + (size_t)(bm + r0) * K + kq;
    const unsigned short* Ap1 = Ap0 + (size_t)16 * K;
    const unsigned short* Bp0 = Bt + (size_t)(bn + r0) * K + kq;
    const unsigned short* Bp1 = Bp0 + (size_t)16 * K;
    const int wo0 = (wave << 5) * 32, wo1 = ((wave << 5) + 16) * 32;

    const int la = lane & 15, h4 = lane >> 4;
    const int sw = (la >> 1) & 3;
    f32x4 acc[4][4] = {};

    for (int k0 = 0; k0 < K; k0 += 64) {
        gld16(Ap0 + k0, &As0[wo0]);      gld16(Ap1 + k0, &As0[wo1]);
        gld16(Bp0 + k0, &Bs0[wo0]);      gld16(Bp1 + k0, &Bs0[wo1]);
        gld16(Ap0 + k0 + 32, &As1[wo0]); gld16(Ap1 + k0 + 32, &As1[wo1]);
        gld16(Bp0 + k0 + 32, &Bs1[wo0]); gld16(Bp1 + k0 + 32, &Bs1[wo1]);
        __syncthreads();
        bf16x8 a[4], b[4];
#pragma unroll
        for (int i = 0; i < 4; ++i) {
            a[i] = *(const bf16x8*)&As0[(wm + i * 16 + la) * 32 + ((h4 ^ sw) << 3)];
            b[i] = *(const bf16x8*)&Bs0[(wn + i * 16 + la) * 32 + ((h4 ^ sw) << 3)];
        }
#pragma unroll
        for (int mi = 0; mi < 4; ++mi)
#pragma unroll
            for (int ni = 0; ni < 4; ++ni)
                acc[mi][ni] = __builtin_amdgcn_mfma_f32_16x16x32_bf16(a[mi], b[ni], acc[mi][ni], 0, 0, 0);
#pragma unroll
        for (int i = 0; i < 4; ++i) {
            a[i] = *(const bf16x8*)&As1[(wm + i * 16 + la) * 32 + ((h4 ^ sw) << 3)];
            b[i] = *(const bf16x8*)&Bs1[(wn + i * 16 + la) * 32 + ((h4 ^ sw) << 3)];
        }
#pragma unroll
        for (int mi = 0; mi < 4; ++mi)
#pragma unroll
            for (int ni = 0; ni < 4; ++ni)
                acc[mi][ni] = __builtin_amdgcn_mfma_f32_16x16x32_bf16(a[mi], b[ni], acc[mi][ni], 0, 0, 0);
        __syncthreads();
    }

#pragma unroll
    for (int mi = 0; mi < 4; ++mi) {
#pragma unroll
        for (int r = 0; r < 4; ++r) {
            int m = bm + wm + mi * 16 + h4 * 4 + r;
#pragma unroll
            for (int ni = 0; ni < 4; ++ni) {
                int n2 = nb + wn + ni * 16 + la;
                float c = acc[mi][ni][r] + bias[n2];
                size_t o = (size_t)m * 512 + n2;
                unsigned short hb = f2bf(c);
                oh[o] = hb;
                if (ol) ol[o] = f2bf(c - bf2f(hb));
            }
        }
    }
}

// transpose + cast: W [R][Cc] f32 -> Wt [Cc][R] bf16 (FF weights)
__global__ __launch_bounds__(256)
void tcast_kernel(const float* __restrict__ W, unsigned short* __restrict__ Wt, int R, int Cc)
{
    __shared__ float t[32][33];
    int bx = blockIdx.x * 32, by = blockIdx.y * 32;
    int tx = threadIdx.x & 31, ty = threadIdx.x >> 5;
#pragma unroll
    for (int i = 0; i < 32; i += 8)
        t[ty + i][tx] = W[(size_t)(by + ty + i) * Cc + bx + tx];
    __syncthreads();
#pragma unroll
    for (int i = 0; i < 32; i += 8)
        Wt[(size_t)(bx + ty + i) * R + by + tx] = f2bf(t[tx][ty + i]);
}

// batched transpose+cast of 16 512x512 attention weights in one dispatch
struct P16 { const float* p[16]; };
__global__ __launch_bounds__(256)
void tcast_all(P16 srcs, unsigned short* __restrict__ dst)
{
    __shared__ float t[32][33];
    const float* W = srcs.p[blockIdx.z];
    unsigned short* Wt = dst + (size_t)blockIdx.z * 262144;
    int bx = blockIdx.x * 32, by = blockIdx.y * 32;
    int tx = threadIdx.x & 31, ty = threadIdx.x >> 5;
#pragma unroll
    for (int i = 0; i < 32; i += 8)
        t[ty + i][tx] = W[(size_t)(by + ty + i) * 512 + bx + tx];
    __syncthreads();
#pragma unroll
    for (int i = 0; i < 32; i += 8)
        Wt[(size_t)(bx + ty + i) * 512 + by + tx] = f2bf(t[tx][ty + i]);
}

// Positional-embedding table: PE[l][n], l<1024, n<512. Same float ops as the
// old in-emb computation -> bit-identical values; shared by enc and dec emb.
__global__ __launch_bounds__(256)
void pegen_kernel(float* __restrict__ PE)
{
    int idx = blockIdx.x * blockDim.x + threadIdx.x;   // 524288
    int n = idx & 511, l = idx >> 9;
    int i2 = n & ~1;
    float div = expf(-(float)i2 * 0.017988946039015984f);
    float ang = (float)l * div;
    PE[idx] = (n & 1) ? cosf(ang) : sinf(ang);
}

// ---------------------------------------------------------------------------
// Fused embedding: X = conv3(A, W) + posemb(table), AB = bf16(X).
// ---------------------------------------------------------------------------
__global__ __launch_bounds__(256)
void emb_kernel(const float* __restrict__ A, const float* __restrict__ W,
                const float* __restrict__ PEt,
                float* __restrict__ Xo, unsigned short* __restrict__ Xb)
{
    __shared__ float As[66][68];
    __shared__ float Ws[3][64][64];
    const int tid = threadIdx.x;
    const int bn = blockIdx.x * 64, bm = blockIdx.y * 64;
    const int base = bm & ~1023;
    for (int i = tid; i < 66 * 64; i += 256) {
        int r = i >> 6, c = i & 63;
        int l = (bm - base) + r - 1;
        if (l < 0) l += 1024; else if (l >= 1024) l -= 1024;
        As[r][c] = A[(size_t)(base + l) * 64 + c];
    }
    for (int i = tid; i < 3 * 64 * 64; i += 256) {
        int tap = i >> 12, rem = i & 4095, k = rem >> 6, c = rem & 63;
        Ws[tap][k][c] = W[((size_t)tap * 64 + k) * 512 + bn + c];
    }
    __syncthreads();
    const int tx = tid & 15, ty = tid >> 4;
    float acc[4][4] = {};
    for (int tap = 0; tap < 3; ++tap)
        for (int k = 0; k < 64; ++k) {
            f4 bv = *(const f4*)&Ws[tap][k][tx * 4];
#pragma unroll
            for (int i = 0; i < 4; ++i) {
                float a = As[ty * 4 + i + tap][k];
#pragma unroll
                for (int j = 0; j < 4; ++j)
                    acc[i][j] = fmaf(a, bv[j], acc[i][j]);
            }
        }
#pragma unroll
    for (int i = 0; i < 4; ++i) {
        int m = bm + ty * 4 + i;
        int l = m & 1023;
#pragma unroll
        for (int j = 0; j < 4; ++j) {
            int n = bn + tx * 4 + j;
            float c = acc[i][j] + PEt[((size_t)l << 9) + n];
            size_t o = (size_t)m * 512 + n;
            Xo[o] = c;
            Xb[o] = f2bf(c);
        }
    }
}

// ---------------------------------------------------------------------------
// Fused tail v5: 8 K-chunks of 64 (grid 512x8), per-16k staging.
// ---------------------------------------------------------------------------
__global__ __launch_bounds__(256)
void tail_kernel(const float* __restrict__ TSUM, const float* __restrict__ T1,
                 const float* __restrict__ Wt, const float* __restrict__ pw,
                 float* __restrict__ PC, float* __restrict__ PP)
{
    __shared__ float Ts[18][17];
    __shared__ float T1s[16][17];
    __shared__ float Ws[3][16][64];
    __shared__ float Ps[16][64];
    const int tid = threadIdx.x;
    const int bo = blockIdx.x * 16;
    const int kc = blockIdx.y;
    const int b = bo >> 9;
    const int lbase = (bo & 511) + 512;
    const size_t rowbase = (size_t)b << 10;
    const int tc4 = (tid & 15) * 4;
    const int tr = tid >> 4;
    const int kbeg = kc * 64, kend = kbeg + 64;
    float cacc[4] = {}, pacc[4] = {};

    for (int k0 = kbeg; k0 < kend; k0 += 16) {
        for (int i = tid; i < 18 * 16; i += 256) {
            int r = i >> 4, c = i & 15;
            int l = lbase + r - 1; if (l >= 1024) l -= 1024;
            Ts[r][c] = TSUM[(rowbase + l) * 512 + k0 + c];
        }
        {
            int r = tid >> 4, c = tid & 15;
            T1s[r][c] = T1[(rowbase + lbase + r) * 512 + k0 + c];
        }
        for (int i = tid; i < 3 * 16 * 16; i += 256) {
            int tap = i / 256, rem = i & 255, k = rem >> 4, c4 = (rem & 15) * 4;
            *(f4*)&Ws[tap][k][c4] = *(const f4*)&Wt[((size_t)tap * 512 + k0 + k) * 64 + c4];
        }
        if (tid < 256) {
            int k = tid >> 4, c4 = (tid & 15) * 4;
            *(f4*)&Ps[k][c4] = *(const f4*)&pw[(size_t)(k0 + k) * 64 + c4];
        }
        __syncthreads();
        for (int tap = 0; tap < 3; ++tap)
#pragma unroll
            for (int k = 0; k < 16; ++k) {
                f4 bv = *(const f4*)&Ws[tap][k][tc4];
                float a = Ts[tr + tap][k];
#pragma unroll
                for (int j = 0; j < 4; ++j)
                    cacc[j] = fmaf(a, bv[j], cacc[j]);
            }
#pragma unroll
        for (int k = 0; k < 16; ++k) {
            f4 bv = *(const f4*)&Ps[k][tc4];
            float a = T1s[tr][k];
#pragma unroll
            for (int j = 0; j < 4; ++j)
                pacc[j] = fmaf(a, bv[j], pacc[j]);
        }
        __syncthreads();
    }
    size_t o = ((size_t)kc * 8192 + (bo + tr)) * 64 + tc4;
    *(f4*)&PC[o] = *(f4*)cacc;
    *(f4*)&PP[o] = *(f4*)pacc;
}

// OUT = (MEANC + sum_kc PC) + (sum_kc PP + pb), chunk-ascending (deterministic)
__global__ __launch_bounds__(256)
void tailred_kernel(const float* __restrict__ PC, const float* __restrict__ PP,
                    const float* __restrict__ MEANC, const float* __restrict__ pb,
                    float* __restrict__ OUT)
{
    int idx = blockIdx.x * blockDim.x + threadIdx.x;
    int n = idx & 63;
    int b = idx >> 15;
    const size_t S = (size_t)8192 * 64;
    float cs = PC[idx];
    float ps = PP[idx];
#pragma unroll
    for (int s = 1; s < 8; ++s) {
        cs += PC[s * S + idx];
        ps += PP[s * S + idx];
    }
    OUT[idx] = (MEANC[(b << 6) + n] + cs) + (ps + pb[n]);
}

// ---------------------------------------------------------------------------
// Autocorrelation scores v6: 256x256 tiles, 512 threads (2Mx4N waves), BK=32,
// double-buffered prefetch (1 block/CU, 77.5us measured r27). LDS 144KB.
// ---------------------------------------------------------------------------
__global__ __launch_bounds__(512)
void corr_mfma(const unsigned short* __restrict__ Qh, const unsigned short* __restrict__ Ql,
               const unsigned short* __restrict__ Kh, const unsigned short* __restrict__ Kl,
               float* __restrict__ G)
{
    __shared__ unsigned short Qhs[2][8192], Qls[2][8192], Khs[2][8192], Kls[2][8192];
    __shared__ float diagw[8][512];
    const int tid = threadIdx.x;
    const int wave = tid >> 6, lane = tid & 63;

    // XCD batch-clustering swizzle: 32 blocks/XCD slot = 2 batches x 16 tiles
    const int i_ = blockIdx.x;
    const int x_ = i_ & 7, j_ = i_ >> 3;          // j_: 0..31
    const int b = x_ + ((j_ >> 4) << 3);          // batches {x_, x_+8}
    const int tile = j_ & 15;
    const int bt = (tile >> 2) * 256, bs = (tile & 3) * 256;

    const int wm = (wave >> 2) << 7, wn = (wave & 3) << 6;
    const size_t boff = (size_t)b << 19;

    const int r0 = (wave << 5) + (lane >> 2);
    const int kq = (((lane & 3) ^ ((lane >> 3) & 3)) << 3);   // swizzled source slot
    const size_t g0 = boff + (size_t)(bt + r0) * 512 + kq;
    const size_t g1 = g0 + (size_t)16 * 512;
    const size_t p0 = boff + (size_t)(bs + r0) * 512 + kq;
    const size_t p1 = p0 + (size_t)16 * 512;
    const int wo0 = (wave << 5) * 32, wo1 = ((wave << 5) + 16) * 32;

    {   // zero diag accumulators (covered by the prologue barrier)
        float* dz = &diagw[0][0];
#pragma unroll
        for (int i = 0; i < 8; ++i) dz[tid + i * 512] = 0.f;
    }

    const int la = lane & 15, h4 = lane >> 4;
    const int sw = (la >> 1) & 3;
    f32x4 acc[8][4] = {};

    // prologue: stage K-step 0 into buffer 0
    gld16(Qh + g0, &Qhs[0][wo0]); gld16(Qh + g1, &Qhs[0][wo1]);
    gld16(Ql + g0, &Qls[0][wo0]); gld16(Ql + g1, &Qls[0][wo1]);
    gld16(Kh + p0, &Khs[0][wo0]); gld16(Kh + p1, &Khs[0][wo1]);
    gld16(Kl + p0, &Kls[0][wo0]); gld16(Kl + p1, &Kls[0][wo1]);
    __syncthreads();

    for (int t = 0; t < 16; ++t) {
        if (t + 1 < 16) {   // prefetch next K-step into the other buffer
            const int k0 = (t + 1) << 5;
            const int nb2 = (t + 1) & 1;
            gld16(Qh + g0 + k0, &Qhs[nb2][wo0]); gld16(Qh + g1 + k0, &Qhs[nb2][wo1]);
            gld16(Ql + g0 + k0, &Qls[nb2][wo0]); gld16(Ql + g1 + k0, &Qls[nb2][wo1]);
            gld16(Kh + p0 + k0, &Khs[nb2][wo0]); gld16(Kh + p1 + k0, &Khs[nb2][wo1]);
            gld16(Kl + p0 + k0, &Kls[nb2][wo0]); gld16(Kl + p1 + k0, &Kls[nb2][wo1]);
        }
        const int cb = t & 1;
        bf16x8 ah[8], bh[4];
#pragma unroll
        for (int i = 0; i < 8; ++i)
            ah[i] = *(const bf16x8*)&Qhs[cb][(wm + i * 16 + la) * 32 + ((h4 ^ sw) << 3)];
#pragma unroll
        for (int i = 0; i < 4; ++i)
            bh[i] = *(const bf16x8*)&Khs[cb][(wn + i * 16 + la) * 32 + ((h4 ^ sw) << 3)];
#pragma unroll
        for (int mi = 0; mi < 8; ++mi)
#pragma unroll
            for (int ni = 0; ni < 4; ++ni)
                acc[mi][ni] = __builtin_amdgcn_mfma_f32_16x16x32_bf16(ah[mi], bh[ni], acc[mi][ni], 0, 0, 0);
        {   // hi x lo
            bf16x8 bl[4];
#pragma unroll
            for (int i = 0; i < 4; ++i)
                bl[i] = *(const bf16x8*)&Kls[cb][(wn + i * 16 + la) * 32 + ((h4 ^ sw) << 3)];
#pragma unroll
            for (int mi = 0; mi < 8; ++mi)
#pragma unroll
                for (int ni = 0; ni < 4; ++ni)
                    acc[mi][ni] = __builtin_amdgcn_mfma_f32_16x16x32_bf16(ah[mi], bl[ni], acc[mi][ni], 0, 0, 0);
        }
        {   // lo x hi
            bf16x8 al[8];
#pragma unroll
            for (int i = 0; i < 8; ++i)
                al[i] = *(const bf16x8*)&Qls[cb][(wm + i * 16 + la) * 32 + ((h4 ^ sw) << 3)];
#pragma unroll
            for (int mi = 0; mi < 8; ++mi)
#pragma unroll
                for (int ni = 0; ni < 4; ++ni)
                    acc[mi][ni] = __builtin_amdgcn_mfma_f32_16x16x32_bf16(al[mi], bh[ni], acc[mi][ni], 0, 0, 0);
        }
        __syncthreads();   // drains prefetch (had full compute phase to land)
    }

    // fold accs into per-thread diagonal bins
    float rbin[11][4] = {};
#pragma unroll
    for (int mi = 0; mi < 8; ++mi)
#pragma unroll
        for (int ni = 0; ni < 4; ++ni)
#pragma unroll
            for (int r = 0; r < 4; ++r)
                rbin[mi - ni + 3][r] += acc[mi][ni][r];

    const int base = (wm - wn) + 4 * h4 - la + 255;
#pragma unroll
    for (int d = 0; d < 11; ++d)
#pragma unroll
        for (int r = 0; r < 4; ++r)
            atomicAdd(&diagw[wave][base + 16 * (d - 3) + r], rbin[d][r]);
    __syncthreads();
    if (tid < 511) {
        float s = 0.f;
#pragma unroll
        for (int w = 0; w < 8; ++w) s += diagw[w][tid];
        int n = (bt - bs + tid - 255) & 1023;
        atomicAdd(&G[(b << 10) + n], s);
    }
}

// ---------------------------------------------------------------------------
// Per-batch top-20 + softmax, parallel argmax (tie -> lowest index).
// ---------------------------------------------------------------------------
__global__ __launch_bounds__(256)
void topk_kernel(const float* __restrict__ G, int* __restrict__ delay,
                 float* __restrict__ tc)
{
    __shared__ float vals[1024];
    __shared__ float pw[4];
    __shared__ int   pwi[4];
    __shared__ float wsel[TOPK_];
    __shared__ int   isel[TOPK_];
    const int b = blockIdx.x, tid = threadIdx.x;
    const int lane = tid & 63, wid = tid >> 6;
    for (int i = tid; i < 1024; i += 256) vals[i] = G[(b << 10) + i] * (1.0f / 512.0f);
    __syncthreads();
    for (int it = 0; it < TOPK_; ++it) {
        float bv = -INFINITY; int bi = 0;
#pragma unroll
        for (int u = 0; u < 4; ++u) {
            int i = tid * 4 + u;
            float v = vals[i];
            if (v > bv) { bv = v; bi = i; }
        }
#pragma unroll
        for (int o = 32; o > 0; o >>= 1) {
            float ov = __shfl_xor(bv, o, 64);
            int   oi = __shfl_xor(bi, o, 64);
            if (ov > bv || (ov == bv && oi < bi)) { bv = ov; bi = oi; }
        }
        if (lane == 0) { pw[wid] = bv; pwi[wid] = bi; }
        __syncthreads();
        if (tid == 0) {
            float m = pw[0]; int mi = pwi[0];
#pragma unroll
            for (int t = 1; t < 4; ++t)
                if (pw[t] > m || (pw[t] == m && pwi[t] < mi)) { m = pw[t]; mi = pwi[t]; }
            wsel[it] = m; isel[it] = mi;
            vals[mi] = -INFINITY;
        }
        __syncthreads();
    }
    if (tid == 0) {
        float m = wsel[0];
#pragma unroll
        for (int i = 1; i < TOPK_; ++i) m = fmaxf(m, wsel[i]);
        float e[TOPK_], s = 0.f;
#pragma unroll
        for (int i = 0; i < TOPK_; ++i) { e[i] = expf(wsel[i] - m); s += e[i]; }
        float inv = 1.0f / s;
#pragma unroll
        for (int i = 0; i < TOPK_; ++i) {
            tc[b * TOPK_ + i] = e[i] * inv;
            delay[b * TOPK_ + i] = isel[i];
        }
    }
}

// out[b,l,d] = sum_i tc[b,i] * V[b,(l+delay)%1024,d], bf16 in/out, 8-wide.
// delay/tc hoisted to LDS once per block; XCD batch-clustering swizzle.
__global__ __launch_bounds__(256)
void agg_kernel(const unsigned short* __restrict__ V, const int* __restrict__ delay,
                const float* __restrict__ tc, unsigned short* __restrict__ out)
{
    __shared__ int   dls[TOPK_];
    __shared__ float tcs[TOPK_];
    int h = blockIdx.x, g = gridDim.x, lh = h;
    if ((g & 7) == 0) {
        int q = g >> 3;
        lh = (h & 7) * q + (h >> 3);
    }
    int idx = (lh * blockDim.x + threadIdx.x) * 8;
    int d = idx & 511;
    int l = (idx >> 9) & 1023;
    int b = idx >> 19;
    if (threadIdx.x < TOPK_) {
        dls[threadIdx.x] = delay[b * TOPK_ + threadIdx.x];
        tcs[threadIdx.x] = tc[b * TOPK_ + threadIdx.x];
    }
    __syncthreads();
    const unsigned short* Vb = V + ((size_t)b << 19);
    float s[8] = {};
#pragma unroll
    for (int i = 0; i < TOPK_; ++i) {
        int row = (l + dls[i]) & 1023;
        float w = tcs[i];
        u16x8 v = *(const u16x8*)&Vb[((size_t)row << 9) + d];
#pragma unroll
        for (int j = 0; j < 8; ++j)
            s[j] = fmaf(w, bf2f(v[j]), s[j]);
    }
    u16x8 o;
#pragma unroll
    for (int j = 0; j < 8; ++j) o[j] = f2bf(s[j]);
    *(u16x8*)&out[idx] = o;
}

// ---------------------------------------------------------------------------
// series_decomp with optional bf16 dual-out of the seasonal part.
// XCD swizzle clusters each batch's blocks on one XCD. Bit-identical.
// ---------------------------------------------------------------------------
__global__ void decomp_kernel(const float* __restrict__ x, float* __restrict__ seas,
                              unsigned short* __restrict__ seasb,
                              float* __restrict__ trend, int Bn, int Ln, int Ch,
                              int nseg, int tmode)
{
    int h = blockIdx.x, g = gridDim.x, lh = h;
    if ((g & 7) == 0) {
        int q = g >> 3;
        lh = (h & 7) * q + (h >> 3);
    }
    int idx = lh * blockDim.x + threadIdx.x;
    int total = Bn * Ch * nseg;
    if (idx >= total) return;
    int ch = idx % Ch;
    int rest = idx / Ch;
    int seg = rest % nseg;
    int b = rest / nseg;
    int segL = Ln / nseg;
    int l0 = seg * segL;
    const float* xp = x + (size_t)b * Ln * Ch + ch;
    float* sp = seas + (size_t)b * Ln * Ch + ch;
    unsigned short* bp = seasb ? seasb + (size_t)b * Ln * Ch + ch : nullptr;
    float* tp = trend ? trend + (size_t)b * Ln * Ch + ch : nullptr;
    float s = 0.f;
    for (int j = -12; j <= 12; ++j) {
        int t = l0 + j;
        t = t < 0 ? 0 : (t > Ln - 1 ? Ln - 1 : t);
        s += xp[(size_t)t * Ch];
    }
    for (int l = l0; l < l0 + segL; ++l) {
        float mm = s * (1.0f / 25.0f);
        float v = xp[(size_t)l * Ch] - mm;
        sp[(size_t)l * Ch] = v;
        if (bp) bp[(size_t)l * Ch] = f2bf(v);
        if (tmode == 1) tp[(size_t)l * Ch] = mm;
        else if (tmode == 2) tp[(size_t)l * Ch] += mm;
        int ta = l + 13; if (ta > Ln - 1) ta = Ln - 1;
        int ts = l - 12; if (ts < 0) ts = 0;
        s += xp[(size_t)ta * Ch] - xp[(size_t)ts * Ch];
    }
}

__global__ __launch_bounds__(256)
void lnrow_kernel(const float* __restrict__ x, const float* __restrict__ g,
                  const float* __restrict__ bv, float* __restrict__ out)
{
    __shared__ float sh1[4], sh2[4];
    int row = blockIdx.x, tid = threadIdx.x;
    const float* xr = x + ((size_t)row << 9);
    float v0 = xr[tid], v1 = xr[tid + 256];
    float s = v0 + v1, q = v0 * v0 + v1 * v1;
#pragma unroll
    for (int o = 32; o > 0; o >>= 1) {
        s += __shfl_down(s, o, 64);
        q += __shfl_down(q, o, 64);
    }
    int wid = tid >> 6;
    if ((tid & 63) == 0) { sh1[wid] = s; sh2[wid] = q; }
    __syncthreads();
    if (tid == 0) {
        sh1[0] = sh1[0] + sh1[1] + sh1[2] + sh1[3];
        sh2[0] = sh2[0] + sh2[1] + sh2[2] + sh2[3];
    }
    __syncthreads();
    float mu = sh1[0] * (1.0f / 512.0f);
    float var = sh2[0] * (1.0f / 512.0f) - mu * mu;
    float inv = rsqrtf(var + 1e-5f);
    out[((size_t)row << 9) + tid] = (v0 - mu) * inv * g[tid] + bv[tid];
    out[((size_t)row << 9) + tid + 256] = (v1 - mu) * inv * g[tid + 256] + bv[tid + 256];
}

__global__ void colmean_kernel(const float* __restrict__ x, float* __restrict__ m)
{
    int idx = blockIdx.x * blockDim.x + threadIdx.x;
    if (idx >= B_ * D_) return;
    int b = idx >> 9, d = idx & 511;
    const float* xp = x + ((size_t)b << 19) + d;
    float s = 0.f;
    for (int l = 0; l < L_; ++l) s += xp[(size_t)l << 9];
    m[idx] = s * (1.0f / 1024.0f);
}

// out_bf16 = x - colmean (encoder output, bf16 only)
__global__ void colsub_kernel(const float* __restrict__ x, const float* __restrict__ m,
                              unsigned short* __restrict__ out)
{
    int idx = blockIdx.x * blockDim.x + threadIdx.x;
    int d = idx & 511;
    int b = idx >> 19;
    out[idx] = f2bf(x[idx] - m[(b << 9) + d]);
}

__global__ void meanx_kernel(const float* __restrict__ x, float* __restrict__ m)
{
    int idx = blockIdx.x * blockDim.x + threadIdx.x;
    if (idx >= B_ * C_) return;
    int b = idx >> 6, c = idx & 63;
    const float* xp = x + (size_t)b * L_ * C_ + c;
    float s = 0.f;
    for (int l = 0; l < L_; ++l) s += xp[(size_t)l << 6];
    m[idx] = s * (1.0f / 1024.0f);
}

// build decoder seasonal input only (trend tail == meanc, consumed directly)
__global__ void builddec_kernel(const float* __restrict__ seenc, float* __restrict__ seasin)
{
    int idx = blockIdx.x * blockDim.x + threadIdx.x;
    int c = idx & 63;
    int l = (idx >> 6) & 1023;
    int b = idx >> 16;
    if (l < 512) {
        int src = (b << 16) + ((512 + l) << 6) + c;
        seasin[idx] = seenc[src];
    } else {
        seasin[idx] = 0.f;
    }
}

// ---------------------------------------------------------------------------
extern "C" void kernel_launch(void* const* d_in, const int* in_sizes, int n_in,
                              void* d_out, int out_size, void* d_ws, size_t ws_size,
                              hipStream_t stream)
{
    auto F = [&](int i) { return (const float*)d_in[i]; };
    const float* x_enc     = F(0);
    const float* enc_emb_w = F(2);
    const float* dec_emb_w = F(3);
    const float* enc_Wq = F(4);  const float* enc_bq = F(5);
    const float* dsa_Wq = F(6);  const float* dsa_bq = F(7);
    const float* dca_Wq = F(8);  const float* dca_bq = F(9);
    const float* enc_Wk = F(10); const float* enc_bk = F(11);
    const float* dsa_Wk = F(12); const float* dsa_bk = F(13);
    const float* dca_Wk = F(14); const float* dca_bk = F(15);
    const float* enc_Wv = F(16); const float* enc_bv = F(17);
    const float* dsa_Wv = F(18); const float* dsa_bv = F(19);
    const float* dca_Wv = F(20); const float* dca_bv = F(21);
    const float* enc_Wo = F(22); const float* enc_bo = F(23);
    const float* dsa_Wo = F(24); const float* dsa_bo = F(25);
    const float* dca_Wo = F(26); const float* dca_bo = F(27);
    const float* enc_ff1 = F(28); const float* enc_ff2 = F(29);
    const float* enc_ng = F(30);  const float* enc_nb = F(31);
    const float* dec_ff1 = F(32); const float* dec_ff2 = F(33);
    const float* dec_trend_w = F(34);
    const float* proj_w = F(35);  const float* proj_b = F(36);

    constexpr size_t F512 = (size_t)B_ * L_ * D_;   // 8388608
    constexpr size_t F64  = (size_t)B_ * L_ * C_;   // 1048576
    constexpr size_t SMALL = 1024 + 16384 + 320 + 320 + 8192;
    constexpr size_t WTSA_N = 16 * 262144;          // persistent attn weights (bf16)
    constexpr size_t WTSF_N = 2 * 1024 * 1024;      // ff weight scratch (bf16)
    size_t need = (3 * F512 + 2 * F64 + SMALL) * 4 + (8 * F512 + WTSA_N + WTSF_N) * 2;
    if (ws_size < need) return;

    float* X      = (float*)d_ws;
    float* T1     = X + F512;
    float* TSUM   = T1 + F512;
    float* SEASIN = TSUM + F512;
    float* PET    = SEASIN + F64;   // posemb table (524288 floats, slab is F64)
    float* MEANC  = PET + F64;
    float* G      = MEANC + 1024;
    float* TCW    = G + 16384;
    int*   DEL    = (int*)(TCW + 320);
    float* LNMEAN = (float*)(DEL + 320);
    unsigned short* AB   = (unsigned short*)(LNMEAN + 8192);
    unsigned short* EB   = AB + F512;
    unsigned short* VB   = EB + F512;
    unsigned short* HB   = VB + F512;
    unsigned short* QHI  = HB + F512;
    unsigned short* QLO  = QHI + F512;
    unsigned short* KHI  = QLO + F512;
    unsigned short* KLO  = KHI + F512;
    unsigned short* WTSA = KLO + F512;
    unsigned short* WTSF = WTSA + WTSA_N;
    float* OUT = (float*)d_out;

    const int M = B_ * L_;  // 16384

    auto mgemm = [&](const unsigned short* A, const unsigned short* Bt, float* Cf,
                     unsigned short* Cb, unsigned short* Cl, const float* bias,
                     int Mm, int Nn, int Kk, int flags) {
        int nx = Nn / 128;
        int total = nx * (Mm / 128);
        gemm_bf16<<<total, 256, 0, stream>>>(A, Bt, Cf, Cb, Cl, bias, Mm, Nn, Kk, flags, nx);
    };
    auto tcast = [&](const float* W, unsigned short* Wt, int R, int Cc) {
        tcast_kernel<<<dim3(Cc / 32, R / 32), 256, 0, stream>>>(W, Wt, R, Cc);
    };
    auto corr_topk_agg = [&]() {
        corr_mfma<<<256, 512, 0, stream>>>(QHI, QLO, KHI, KLO, G);
        topk_kernel<<<16, 256, 0, stream>>>(G, DEL, TCW);
        agg_kernel<<<(int)(F512 / 8 / 256), 256, 0, stream>>>(VB, DEL, TCW, HB);
    };
    // self-attn: Q,K,V in one merged GEMM (weight slots contiguous); zeroes G
    auto attn_self = [&](const unsigned short* xin, int slotbase,
                         const float* bq, const float* bk, const float* bvp, const float* bo,
                         float* resid) {
        gemm_split<<<12 * 128, 256, 0, stream>>>(xin, WTSA + (size_t)slotbase * 262144,
            QHI, QLO, bq, KHI, KLO, bk, VB, nullptr, bvp, G, M, 1536, 512, 12);
        corr_topk_agg();
        mgemm(HB, WTSA + (size_t)(slotbase + 3) * 262144, resid, nullptr, nullptr, bo, M, 512, 512, 1);
    };
    // cross-attn: Q separate (different input); K,V merged (zeroes G)
    auto attn_cross = [&](const unsigned short* qin, const unsigned short* kvin, int slotbase,
                          const float* bq, const float* bk, const float* bvp, const float* bo,
                          float* resid) {
        mgemm(qin, WTSA + (size_t)slotbase * 262144, nullptr, QHI, QLO, bq, M, 512, 512, 0);
        gemm_split<<<8 * 128, 256, 0, stream>>>(kvin, WTSA + (size_t)(slotbase + 1) * 262144,
            KHI, KLO, bk, VB, nullptr, bvp, nullptr, nullptr, nullptr, G, M, 1024, 512, 8);
        corr_topk_agg();
        mgemm(HB, WTSA + (size_t)(slotbase + 3) * 262144, resid, nullptr, nullptr, bo, M, 512, 512, 1);
    };
    auto ffblock = [&](const unsigned short* xin, const float* W1, const float* W2, float* resid) {
        unsigned short* Wf1 = WTSF;
        unsigned short* Wf2 = WTSF + 1048576;
        unsigned short* HFULL = QHI;   // spans QHI..KLO exactly (4*F512 elems)
        tcast(W1, Wf1, 512, 2048);
        tcast(W2, Wf2, 2048, 512);
        gemm256_gelu<<<512, 512, 0, stream>>>(xin, Wf1, HFULL, M, 2048, 512, 8);
        gemm256_ffr<<<256, 512, 0, stream>>>(HFULL, Wf2, resid, M, 512, 2048);
    };

    // ---------------- upfront: batched attn weight transpose + PE table -----
    {
        P16 srcs;
        for (int l = 0; l < 2; ++l) {
            srcs.p[l * 4 + 0] = enc_Wq + (size_t)l * 262144;
            srcs.p[l * 4 + 1] = enc_Wk + (size_t)l * 262144;
            srcs.p[l * 4 + 2] = enc_Wv + (size_t)l * 262144;
            srcs.p[l * 4 + 3] = enc_Wo + (size_t)l * 262144;
        }
        srcs.p[8]  = dsa_Wq; srcs.p[9]  = dsa_Wk; srcs.p[10] = dsa_Wv; srcs.p[11] = dsa_Wo;
        srcs.p[12] = dca_Wq; srcs.p[13] = dca_Wk; srcs.p[14] = dca_Wv; srcs.p[15] = dca_Wo;
        tcast_all<<<dim3(16, 16, 16), 256, 0, stream>>>(srcs, WTSA);
    }
    pegen_kernel<<<2048, 256, 0, stream>>>(PET);

    // ---------------- prep: decomposition of x_enc, decoder inits -----------
    float* SEENC = (float*)QHI;   // alias: prep phase only
    decomp_kernel<<<(B_ * C_ * 64 + 255) / 256, 256, 0, stream>>>(x_enc, SEENC, nullptr, nullptr, B_, L_, C_, 64, 0);
    meanx_kernel<<<(B_ * C_ + 255) / 256, 256, 0, stream>>>(x_enc, MEANC);
    builddec_kernel<<<(int)(F64 / 256), 256, 0, stream>>>(SEENC, SEASIN);

    // ---------------- encoder ----------------------------------------------
    emb_kernel<<<dim3(8, 256), 256, 0, stream>>>(x_enc, enc_emb_w, PET, X, AB);

    for (int l = 0; l < 2; ++l) {
        attn_self(AB, l * 4,
                  enc_bq + l * D_, enc_bk + l * D_, enc_bv + l * D_, enc_bo + l * D_, X);
        decomp_kernel<<<(B_ * D_ * 64 + 255) / 256, 256, 0, stream>>>(X, T1, AB, nullptr, B_, L_, D_, 64, 0);
        ffblock(AB, enc_ff1 + (size_t)l * D_ * DFF_, enc_ff2 + (size_t)l * DFF_ * D_, T1);
        decomp_kernel<<<(B_ * D_ * 64 + 255) / 256, 256, 0, stream>>>(T1, X, AB, nullptr, B_, L_, D_, 64, 0);
    }
    lnrow_kernel<<<M, 256, 0, stream>>>(X, enc_ng, enc_nb, T1);
    colmean_kernel<<<(B_ * D_ + 255) / 256, 256, 0, stream>>>(T1, LNMEAN);
    colsub_kernel<<<(int)(F512 / 256), 256, 0, stream>>>(T1, LNMEAN, EB);

    // ---------------- decoder ----------------------------------------------
    float* XD = X;
    emb_kernel<<<dim3(8, 256), 256, 0, stream>>>(SEASIN, dec_emb_w, PET, XD, AB);

    attn_self(AB, 8, dsa_bq, dsa_bk, dsa_bv, dsa_bo, XD);
    decomp_kernel<<<(B_ * D_ * 64 + 255) / 256, 256, 0, stream>>>(XD, T1, AB, TSUM, B_, L_, D_, 64, 1);

    attn_cross(AB, EB, 12, dca_bq, dca_bk, dca_bv, dca_bo, T1);
    decomp_kernel<<<(B_ * D_ * 64 + 255) / 256, 256, 0, stream>>>(T1, XD, AB, TSUM, B_, L_, D_, 64, 2);

    ffblock(AB, dec_ff1, dec_ff2, XD);
    decomp_kernel<<<(B_ * D_ * 64 + 255) / 256, 256, 0, stream>>>(XD, T1, nullptr, TSUM, B_, L_, D_, 64, 2);

    // fused trend-conv + proj, K-split x8 into partials, then deterministic reduce
    float* PART_C = (float*)QHI;                       // dead slab
    float* PART_P = PART_C + (size_t)8 * 8192 * 64;
    tail_kernel<<<dim3(512, 8), 256, 0, stream>>>(TSUM, T1, dec_trend_w, proj_w, PART_C, PART_P);
    tailred_kernel<<<2048, 256, 0, stream>>>(PART_C, PART_P, MEANC, proj_b, OUT);
}

// Round 29
// 1673.790 us; speedup vs baseline: 1.0444x; 1.0444x over previous
//
#include <hip/hip_runtime.h>
#include <math.h>

#define B_   16
#define L_   1024
#define C_   64
#define D_   512
#define DFF_ 2048
#define TOPK_ 20

typedef float f4 __attribute__((ext_vector_type(4)));
typedef float f32x4 __attribute__((ext_vector_type(4)));
typedef short bf16x8 __attribute__((ext_vector_type(8)));
typedef unsigned short u16x8 __attribute__((ext_vector_type(8)));

__device__ __forceinline__ unsigned short f2bf(float f) {
    union { float f; unsigned u; } a; a.f = f;
    unsigned r = a.u + 0x7fff + ((a.u >> 16) & 1);
    return (unsigned short)(r >> 16);
}
__device__ __forceinline__ float bf2f(unsigned short h) {
    union { unsigned u; float f; } a; a.u = ((unsigned)h) << 16;
    return a.f;
}

// Fast exact-GELU: erf via Abramowitz-Stegun 7.1.26 (|err|<=1.5e-7, far below
// the bf16 output quantum ~4e-3 rel) with native rcp/exp.
__device__ __forceinline__ float gelu_fast(float c) {
    float z  = c * 0.70710678118654752f;
    float az = fabsf(z);
    float t  = __builtin_amdgcn_rcpf(fmaf(0.3275911f, az, 1.0f));
    float p  = fmaf(fmaf(fmaf(fmaf(1.061405429f, t, -1.453152027f), t,
                              1.421413741f), t, -0.284496736f), t, 0.254829592f) * t;
    float e  = __expf(-z * z);
    float ea = fmaf(-p, e, 1.0f);
    float er = copysignf(ea, z);
    return 0.5f * c * (1.0f + er);
}

__device__ __forceinline__ void gld16(const void* g, void* l) {
    __builtin_amdgcn_global_load_lds(
        (const __attribute__((address_space(1))) unsigned int*)g,
        (__attribute__((address_space(3))) unsigned int*)l, 16, 0, 0);
}

// LDS swizzle (all MFMA kernels): permute 16B source slot at staging
// (kq ^= lane row bits) and XOR the read slot identically -> bank-conflict
// free (verified: SQ_LDS_BANK_CONFLICT 4.19M -> 0). Bit-identical data.

// ---------------------------------------------------------------------------
// bf16 MFMA GEMM: C[M,N] = op(A[M,K] @ B[K,N] + bias). BK=64.
// (r28 lesson: FF2 (N=512,K=2048) is A-traffic-bound; split-K atomics only
// multiply traffic. This 128^2 kernel is its best measured form.)
// ---------------------------------------------------------------------------
__global__ __launch_bounds__(256)
void gemm_bf16(const unsigned short* __restrict__ A, const unsigned short* __restrict__ Bt,
               float* __restrict__ Cf, unsigned short* __restrict__ Cb,
               unsigned short* __restrict__ Cl,
               const float* __restrict__ bias, int M, int N, int K, int flags, int nx)
{
    __shared__ unsigned short As0[128 * 32], As1[128 * 32];
    __shared__ unsigned short Bs0[128 * 32], Bs1[128 * 32];
    const int tid = threadIdx.x;
    const int wave = tid >> 6, lane = tid & 63;

    int total = gridDim.x;
    int h = blockIdx.x;
    int lidx = h;
    if ((total & 7) == 0) {
        int q = total >> 3;
        lidx = (h & 7) * q + (h >> 3);
    }
    const int bm = (lidx / nx) * 128, bn = (lidx % nx) * 128;
    const int wm = (wave >> 1) << 6, wn = (wave & 1) << 6;

    const int r0 = (wave << 5) + (lane >> 2);
    const int kq = (((lane & 3) ^ ((lane >> 3) & 3)) << 3);   // swizzled source slot
    const unsigned short* Ap0 = A + (size_t)(bm + r0) * K + kq;
    const unsigned short* Ap1 = Ap0 + (size_t)16 * K;
    const unsigned short* Bp0 = Bt + (size_t)(bn + r0) * K + kq;
    const unsigned short* Bp1 = Bp0 + (size_t)16 * K;
    const int wo0 = (wave << 5) * 32, wo1 = ((wave << 5) + 16) * 32;

    const int la = lane & 15, h4 = lane >> 4;
    const int sw = (la >> 1) & 3;                              // read-side slot XOR
    f32x4 acc[4][4] = {};

    for (int k0 = 0; k0 < K; k0 += 64) {
        gld16(Ap0 + k0, &As0[wo0]);      gld16(Ap1 + k0, &As0[wo1]);
        gld16(Bp0 + k0, &Bs0[wo0]);      gld16(Bp1 + k0, &Bs0[wo1]);
        gld16(Ap0 + k0 + 32, &As1[wo0]); gld16(Ap1 + k0 + 32, &As1[wo1]);
        gld16(Bp0 + k0 + 32, &Bs1[wo0]); gld16(Bp1 + k0 + 32, &Bs1[wo1]);
        __syncthreads();
        bf16x8 a[4], b[4];
#pragma unroll
        for (int i = 0; i < 4; ++i) {
            a[i] = *(const bf16x8*)&As0[(wm + i * 16 + la) * 32 + ((h4 ^ sw) << 3)];
            b[i] = *(const bf16x8*)&Bs0[(wn + i * 16 + la) * 32 + ((h4 ^ sw) << 3)];
        }
#pragma unroll
        for (int mi = 0; mi < 4; ++mi)
#pragma unroll
            for (int ni = 0; ni < 4; ++ni)
                acc[mi][ni] = __builtin_amdgcn_mfma_f32_16x16x32_bf16(a[mi], b[ni], acc[mi][ni], 0, 0, 0);
#pragma unroll
        for (int i = 0; i < 4; ++i) {
            a[i] = *(const bf16x8*)&As1[(wm + i * 16 + la) * 32 + ((h4 ^ sw) << 3)];
            b[i] = *(const bf16x8*)&Bs1[(wn + i * 16 + la) * 32 + ((h4 ^ sw) << 3)];
        }
#pragma unroll
        for (int mi = 0; mi < 4; ++mi)
#pragma unroll
            for (int ni = 0; ni < 4; ++ni)
                acc[mi][ni] = __builtin_amdgcn_mfma_f32_16x16x32_bf16(a[mi], b[ni], acc[mi][ni], 0, 0, 0);
        __syncthreads();
    }

#pragma unroll
    for (int mi = 0; mi < 4; ++mi) {
#pragma unroll
        for (int r = 0; r < 4; ++r) {
            int m = bm + wm + mi * 16 + h4 * 4 + r;
#pragma unroll
            for (int ni = 0; ni < 4; ++ni) {
                int n = bn + wn + ni * 16 + la;
                float c = acc[mi][ni][r];
                if (bias) c += bias[n];
                if (flags & 2) c = gelu_fast(c);
                size_t o = (size_t)m * N + n;
                if (Cf) { if (flags & 1) Cf[o] += c; else Cf[o] = c; }
                if (Cb) {
                    unsigned short hb = f2bf(c);
                    Cb[o] = hb;
                    if (Cl) Cl[o] = f2bf(c - bf2f(hb));
                }
            }
        }
    }
}

// ---------------------------------------------------------------------------
// FF1 GEMM: 256x256 tile, 512 threads (8 waves, 2Mx4N), BK=64, double-buffered
// LDS (128KB) with next-K-step prefetch. 1 block/CU -> dbuf costs nothing.
// GELU epilogue, bf16-out only. Bit-identical K order.
// ---------------------------------------------------------------------------
__global__ __launch_bounds__(512)
void gemm256_gelu(const unsigned short* __restrict__ A, const unsigned short* __restrict__ Bt,
                  unsigned short* __restrict__ Cb, int M, int N, int K, int nx)
{
    __shared__ unsigned short As[2][16384];   // [buf][half*8192 + row*32 + slot]
    __shared__ unsigned short Bs[2][16384];
    const int tid = threadIdx.x;
    const int wave = tid >> 6, lane = tid & 63;

    int total = gridDim.x;
    int h = blockIdx.x;
    int lidx = h;
    if ((total & 7) == 0) {
        int q = total >> 3;
        lidx = (h & 7) * q + (h >> 3);
    }
    const int bm = (lidx / nx) * 256, bn = (lidx % nx) * 256;
    const int wm = (wave >> 2) << 7, wn = (wave & 3) << 6;

    const int r0 = (wave << 5) + (lane >> 2);
    const int kq = (((lane & 3) ^ ((lane >> 3) & 3)) << 3);   // swizzled source slot
    const unsigned short* Ap0 = A + (size_t)(bm + r0) * K + kq;
    const unsigned short* Ap1 = Ap0 + (size_t)16 * K;
    const unsigned short* Bp0 = Bt + (size_t)(bn + r0) * K + kq;
    const unsigned short* Bp1 = Bp0 + (size_t)16 * K;
    const int wo0 = (wave << 5) * 32, wo1 = ((wave << 5) + 16) * 32;

    const int la = lane & 15, h4 = lane >> 4;
    const int sw = (la >> 1) & 3;
    f32x4 acc[8][4] = {};

    // prologue: stage K-step 0 into buffer 0
    gld16(Ap0, &As[0][wo0]);             gld16(Ap1, &As[0][wo1]);
    gld16(Bp0, &Bs[0][wo0]);             gld16(Bp1, &Bs[0][wo1]);
    gld16(Ap0 + 32, &As[0][8192 + wo0]); gld16(Ap1 + 32, &As[0][8192 + wo1]);
    gld16(Bp0 + 32, &Bs[0][8192 + wo0]); gld16(Bp1 + 32, &Bs[0][8192 + wo1]);
    __syncthreads();

    const int nt = K >> 6;
    for (int t = 0; t < nt; ++t) {
        if (t + 1 < nt) {   // prefetch next K-step into the other buffer
            const int k0 = (t + 1) << 6;
            const int nb2 = (t + 1) & 1;
            gld16(Ap0 + k0, &As[nb2][wo0]);             gld16(Ap1 + k0, &As[nb2][wo1]);
            gld16(Bp0 + k0, &Bs[nb2][wo0]);             gld16(Bp1 + k0, &Bs[nb2][wo1]);
            gld16(Ap0 + k0 + 32, &As[nb2][8192 + wo0]); gld16(Ap1 + k0 + 32, &As[nb2][8192 + wo1]);
            gld16(Bp0 + k0 + 32, &Bs[nb2][8192 + wo0]); gld16(Bp1 + k0 + 32, &Bs[nb2][8192 + wo1]);
        }
        const int cb = t & 1;
#pragma unroll
        for (int hh = 0; hh < 2; ++hh) {
            const int hb = hh << 13;
            bf16x8 a[8], b[4];
#pragma unroll
            for (int i = 0; i < 8; ++i)
                a[i] = *(const bf16x8*)&As[cb][hb + (wm + i * 16 + la) * 32 + ((h4 ^ sw) << 3)];
#pragma unroll
            for (int i = 0; i < 4; ++i)
                b[i] = *(const bf16x8*)&Bs[cb][hb + (wn + i * 16 + la) * 32 + ((h4 ^ sw) << 3)];
#pragma unroll
            for (int mi = 0; mi < 8; ++mi)
#pragma unroll
                for (int ni = 0; ni < 4; ++ni)
                    acc[mi][ni] = __builtin_amdgcn_mfma_f32_16x16x32_bf16(a[mi], b[ni], acc[mi][ni], 0, 0, 0);
        }
        __syncthreads();   // drains prefetch (had full compute phase to land)
    }

#pragma unroll
    for (int mi = 0; mi < 8; ++mi)
#pragma unroll
        for (int r = 0; r < 4; ++r) {
            int m = bm + wm + mi * 16 + h4 * 4 + r;
#pragma unroll
            for (int ni = 0; ni < 4; ++ni) {
                int n = bn + wn + ni * 16 + la;
                Cb[(size_t)m * N + n] = f2bf(gelu_fast(acc[mi][ni][r]));
            }
        }
}

// ---------------------------------------------------------------------------
// Merged QKV projection GEMM: N = 1536 (Q|K|V) or 1024 (K|V). BK=64.
// Gz: optional 16384-float buffer zeroed by the first 64 raw blocks.
// ---------------------------------------------------------------------------
__global__ __launch_bounds__(256)
void gemm_split(const unsigned short* __restrict__ A, const unsigned short* __restrict__ Bt,
                unsigned short* __restrict__ o0h, unsigned short* __restrict__ o0l, const float* __restrict__ b0,
                unsigned short* __restrict__ o1h, unsigned short* __restrict__ o1l, const float* __restrict__ b1,
                unsigned short* __restrict__ o2h, unsigned short* __restrict__ o2l, const float* __restrict__ b2,
                float* __restrict__ Gz, int M, int N, int K, int nx)
{
    __shared__ unsigned short As0[128 * 32], As1[128 * 32];
    __shared__ unsigned short Bs0[128 * 32], Bs1[128 * 32];
    const int tid = threadIdx.x;
    const int wave = tid >> 6, lane = tid & 63;

    int total = gridDim.x;
    int h = blockIdx.x;
    if (Gz && h < 64) Gz[h * 256 + tid] = 0.f;
    int lidx = h;
    if ((total & 7) == 0) {
        int q = total >> 3;
        lidx = (h & 7) * q + (h >> 3);
    }
    const int bm = (lidx / nx) * 128, bn = (lidx % nx) * 128;
    const int wm = (wave >> 1) << 6, wn = (wave & 1) << 6;

    const int sel = bn >> 9;
    unsigned short* oh = sel == 0 ? o0h : (sel == 1 ? o1h : o2h);
    unsigned short* ol = sel == 0 ? o0l : (sel == 1 ? o1l : o2l);
    const float* bias  = sel == 0 ? b0  : (sel == 1 ? b1  : b2);
    const int nb = bn & 511;

    const int r0 = (wave << 5) + (lane >> 2);
    const int kq = (((lane & 3) ^ ((lane >> 3) & 3)) << 3);   // swizzled source slot
    const unsigned short* Ap0 = A + (size_t)(bm + r0) * K + kq;
    const unsigned short* Ap1 = Ap0 + (size_t)16 * K;
    const unsigned short* Bp0 = Bt + (size_t)(bn + r0) * K + kq;
    const unsigned short* Bp1 = Bp0 + (size_t)16 * K;
    const int wo0 = (wave << 5) * 32, wo1 = ((wave << 5) + 16) * 32;

    const int la = lane & 15, h4 = lane >> 4;
    const int sw = (la >> 1) & 3;
    f32x4 acc[4][4] = {};

    for (int k0 = 0; k0 < K; k0 += 64) {
        gld16(Ap0 + k0, &As0[wo0]);      gld16(Ap1 + k0, &As0[wo1]);
        gld16(Bp0 + k0, &Bs0[wo0]);      gld16(Bp1 + k0, &Bs0[wo1]);
        gld16(Ap0 + k0 + 32, &As1[wo0]); gld16(Ap1 + k0 + 32, &As1[wo1]);
        gld16(Bp0 + k0 + 32, &Bs1[wo0]); gld16(Bp1 + k0 + 32, &Bs1[wo1]);
        __syncthreads();
        bf16x8 a[4], b[4];
#pragma unroll
        for (int i = 0; i < 4; ++i) {
            a[i] = *(const bf16x8*)&As0[(wm + i * 16 + la) * 32 + ((h4 ^ sw) << 3)];
            b[i] = *(const bf16x8*)&Bs0[(wn + i * 16 + la) * 32 + ((h4 ^ sw) << 3)];
        }
#pragma unroll
        for (int mi = 0; mi < 4; ++mi)
#pragma unroll
            for (int ni = 0; ni < 4; ++ni)
                acc[mi][ni] = __builtin_amdgcn_mfma_f32_16x16x32_bf16(a[mi], b[ni], acc[mi][ni], 0, 0, 0);
#pragma unroll
        for (int i = 0; i < 4; ++i) {
            a[i] = *(const bf16x8*)&As1[(wm + i * 16 + la) * 32 + ((h4 ^ sw) << 3)];
            b[i] = *(const bf16x8*)&Bs1[(wn + i * 16 + la) * 32 + ((h4 ^ sw) << 3)];
        }
#pragma unroll
        for (int mi = 0; mi < 4; ++mi)
#pragma unroll
            for (int ni = 0; ni < 4; ++ni)
                acc[mi][ni] = __builtin_amdgcn_mfma_f32_16x16x32_bf16(a[mi], b[ni], acc[mi][ni], 0, 0, 0);
        __syncthreads();
    }

#pragma unroll
    for (int mi = 0; mi < 4; ++mi) {
#pragma unroll
        for (int r = 0; r < 4; ++r) {
            int m = bm + wm + mi * 16 + h4 * 4 + r;
#pragma unroll
            for (int ni = 0; ni < 4; ++ni) {
                int n2 = nb + wn + ni * 16 + la;
                float c = acc[mi][ni][r] + bias[n2];
                size_t o = (size_t)m * 512 + n2;
                unsigned short hb = f2bf(c);
                oh[o] = hb;
                if (ol) ol[o] = f2bf(c - bf2f(hb));
            }
        }
    }
}

// transpose + cast: W [R][Cc] f32 -> Wt [Cc][R] bf16 (FF weights)
__global__ __launch_bounds__(256)
void tcast_kernel(const float* __restrict__ W, unsigned short* __restrict__ Wt, int R, int Cc)
{
    __shared__ float t[32][33];
    int bx = blockIdx.x * 32, by = blockIdx.y * 32;
    int tx = threadIdx.x & 31, ty = threadIdx.x >> 5;
#pragma unroll
    for (int i = 0; i < 32; i += 8)
        t[ty + i][tx] = W[(size_t)(by + ty + i) * Cc + bx + tx];
    __syncthreads();
#pragma unroll
    for (int i = 0; i < 32; i += 8)
        Wt[(size_t)(bx + ty + i) * R + by + tx] = f2bf(t[tx][ty + i]);
}

// batched transpose+cast of 16 512x512 attention weights in one dispatch
struct P16 { const float* p[16]; };
__global__ __launch_bounds__(256)
void tcast_all(P16 srcs, unsigned short* __restrict__ dst)
{
    __shared__ float t[32][33];
    const float* W = srcs.p[blockIdx.z];
    unsigned short* Wt = dst + (size_t)blockIdx.z * 262144;
    int bx = blockIdx.x * 32, by = blockIdx.y * 32;
    int tx = threadIdx.x & 31, ty = threadIdx.x >> 5;
#pragma unroll
    for (int i = 0; i < 32; i += 8)
        t[ty + i][tx] = W[(size_t)(by + ty + i) * 512 + bx + tx];
    __syncthreads();
#pragma unroll
    for (int i = 0; i < 32; i += 8)
        Wt[(size_t)(bx + ty + i) * 512 + by + tx] = f2bf(t[tx][ty + i]);
}

// Positional-embedding table: PE[l][n], l<1024, n<512. Same float ops as the
// old in-emb computation -> bit-identical values; shared by enc and dec emb.
__global__ __launch_bounds__(256)
void pegen_kernel(float* __restrict__ PE)
{
    int idx = blockIdx.x * blockDim.x + threadIdx.x;   // 524288
    int n = idx & 511, l = idx >> 9;
    int i2 = n & ~1;
    float div = expf(-(float)i2 * 0.017988946039015984f);
    float ang = (float)l * div;
    PE[idx] = (n & 1) ? cosf(ang) : sinf(ang);
}

// ---------------------------------------------------------------------------
// Fused embedding: X = conv3(A, W) + posemb(table), AB = bf16(X).
// ---------------------------------------------------------------------------
__global__ __launch_bounds__(256)
void emb_kernel(const float* __restrict__ A, const float* __restrict__ W,
                const float* __restrict__ PEt,
                float* __restrict__ Xo, unsigned short* __restrict__ Xb)
{
    __shared__ float As[66][68];
    __shared__ float Ws[3][64][64];
    const int tid = threadIdx.x;
    const int bn = blockIdx.x * 64, bm = blockIdx.y * 64;
    const int base = bm & ~1023;
    for (int i = tid; i < 66 * 64; i += 256) {
        int r = i >> 6, c = i & 63;
        int l = (bm - base) + r - 1;
        if (l < 0) l += 1024; else if (l >= 1024) l -= 1024;
        As[r][c] = A[(size_t)(base + l) * 64 + c];
    }
    for (int i = tid; i < 3 * 64 * 64; i += 256) {
        int tap = i >> 12, rem = i & 4095, k = rem >> 6, c = rem & 63;
        Ws[tap][k][c] = W[((size_t)tap * 64 + k) * 512 + bn + c];
    }
    __syncthreads();
    const int tx = tid & 15, ty = tid >> 4;
    float acc[4][4] = {};
    for (int tap = 0; tap < 3; ++tap)
        for (int k = 0; k < 64; ++k) {
            f4 bv = *(const f4*)&Ws[tap][k][tx * 4];
#pragma unroll
            for (int i = 0; i < 4; ++i) {
                float a = As[ty * 4 + i + tap][k];
#pragma unroll
                for (int j = 0; j < 4; ++j)
                    acc[i][j] = fmaf(a, bv[j], acc[i][j]);
            }
        }
#pragma unroll
    for (int i = 0; i < 4; ++i) {
        int m = bm + ty * 4 + i;
        int l = m & 1023;
#pragma unroll
        for (int j = 0; j < 4; ++j) {
            int n = bn + tx * 4 + j;
            float c = acc[i][j] + PEt[((size_t)l << 9) + n];
            size_t o = (size_t)m * 512 + n;
            Xo[o] = c;
            Xb[o] = f2bf(c);
        }
    }
}

// ---------------------------------------------------------------------------
// Fused tail v5: 8 K-chunks of 64 (grid 512x8), per-16k staging.
// ---------------------------------------------------------------------------
__global__ __launch_bounds__(256)
void tail_kernel(const float* __restrict__ TSUM, const float* __restrict__ T1,
                 const float* __restrict__ Wt, const float* __restrict__ pw,
                 float* __restrict__ PC, float* __restrict__ PP)
{
    __shared__ float Ts[18][17];
    __shared__ float T1s[16][17];
    __shared__ float Ws[3][16][64];
    __shared__ float Ps[16][64];
    const int tid = threadIdx.x;
    const int bo = blockIdx.x * 16;
    const int kc = blockIdx.y;
    const int b = bo >> 9;
    const int lbase = (bo & 511) + 512;
    const size_t rowbase = (size_t)b << 10;
    const int tc4 = (tid & 15) * 4;
    const int tr = tid >> 4;
    const int kbeg = kc * 64, kend = kbeg + 64;
    float cacc[4] = {}, pacc[4] = {};

    for (int k0 = kbeg; k0 < kend; k0 += 16) {
        for (int i = tid; i < 18 * 16; i += 256) {
            int r = i >> 4, c = i & 15;
            int l = lbase + r - 1; if (l >= 1024) l -= 1024;
            Ts[r][c] = TSUM[(rowbase + l) * 512 + k0 + c];
        }
        {
            int r = tid >> 4, c = tid & 15;
            T1s[r][c] = T1[(rowbase + lbase + r) * 512 + k0 + c];
        }
        for (int i = tid; i < 3 * 16 * 16; i += 256) {
            int tap = i / 256, rem = i & 255, k = rem >> 4, c4 = (rem & 15) * 4;
            *(f4*)&Ws[tap][k][c4] = *(const f4*)&Wt[((size_t)tap * 512 + k0 + k) * 64 + c4];
        }
        if (tid < 256) {
            int k = tid >> 4, c4 = (tid & 15) * 4;
            *(f4*)&Ps[k][c4] = *(const f4*)&pw[(size_t)(k0 + k) * 64 + c4];
        }
        __syncthreads();
        for (int tap = 0; tap < 3; ++tap)
#pragma unroll
            for (int k = 0; k < 16; ++k) {
                f4 bv = *(const f4*)&Ws[tap][k][tc4];
                float a = Ts[tr + tap][k];
#pragma unroll
                for (int j = 0; j < 4; ++j)
                    cacc[j] = fmaf(a, bv[j], cacc[j]);
            }
#pragma unroll
        for (int k = 0; k < 16; ++k) {
            f4 bv = *(const f4*)&Ps[k][tc4];
            float a = T1s[tr][k];
#pragma unroll
            for (int j = 0; j < 4; ++j)
                pacc[j] = fmaf(a, bv[j], pacc[j]);
        }
        __syncthreads();
    }
    size_t o = ((size_t)kc * 8192 + (bo + tr)) * 64 + tc4;
    *(f4*)&PC[o] = *(f4*)cacc;
    *(f4*)&PP[o] = *(f4*)pacc;
}

// OUT = (MEANC + sum_kc PC) + (sum_kc PP + pb), chunk-ascending (deterministic)
__global__ __launch_bounds__(256)
void tailred_kernel(const float* __restrict__ PC, const float* __restrict__ PP,
                    const float* __restrict__ MEANC, const float* __restrict__ pb,
                    float* __restrict__ OUT)
{
    int idx = blockIdx.x * blockDim.x + threadIdx.x;
    int n = idx & 63;
    int b = idx >> 15;
    const size_t S = (size_t)8192 * 64;
    float cs = PC[idx];
    float ps = PP[idx];
#pragma unroll
    for (int s = 1; s < 8; ++s) {
        cs += PC[s * S + idx];
        ps += PP[s * S + idx];
    }
    OUT[idx] = (MEANC[(b << 6) + n] + cs) + (ps + pb[n]);
}

// ---------------------------------------------------------------------------
// Autocorrelation scores v6: 256x256 tiles, 512 threads (2Mx4N waves), BK=32,
// double-buffered prefetch (1 block/CU, 77.5us measured r27). LDS 144KB.
// ---------------------------------------------------------------------------
__global__ __launch_bounds__(512)
void corr_mfma(const unsigned short* __restrict__ Qh, const unsigned short* __restrict__ Ql,
               const unsigned short* __restrict__ Kh, const unsigned short* __restrict__ Kl,
               float* __restrict__ G)
{
    __shared__ unsigned short Qhs[2][8192], Qls[2][8192], Khs[2][8192], Kls[2][8192];
    __shared__ float diagw[8][512];
    const int tid = threadIdx.x;
    const int wave = tid >> 6, lane = tid & 63;

    // XCD batch-clustering swizzle: 32 blocks/XCD slot = 2 batches x 16 tiles
    const int i_ = blockIdx.x;
    const int x_ = i_ & 7, j_ = i_ >> 3;          // j_: 0..31
    const int b = x_ + ((j_ >> 4) << 3);          // batches {x_, x_+8}
    const int tile = j_ & 15;
    const int bt = (tile >> 2) * 256, bs = (tile & 3) * 256;

    const int wm = (wave >> 2) << 7, wn = (wave & 3) << 6;
    const size_t boff = (size_t)b << 19;

    const int r0 = (wave << 5) + (lane >> 2);
    const int kq = (((lane & 3) ^ ((lane >> 3) & 3)) << 3);   // swizzled source slot
    const size_t g0 = boff + (size_t)(bt + r0) * 512 + kq;
    const size_t g1 = g0 + (size_t)16 * 512;
    const size_t p0 = boff + (size_t)(bs + r0) * 512 + kq;
    const size_t p1 = p0 + (size_t)16 * 512;
    const int wo0 = (wave << 5) * 32, wo1 = ((wave << 5) + 16) * 32;

    {   // zero diag accumulators (covered by the prologue barrier)
        float* dz = &diagw[0][0];
#pragma unroll
        for (int i = 0; i < 8; ++i) dz[tid + i * 512] = 0.f;
    }

    const int la = lane & 15, h4 = lane >> 4;
    const int sw = (la >> 1) & 3;
    f32x4 acc[8][4] = {};

    // prologue: stage K-step 0 into buffer 0
    gld16(Qh + g0, &Qhs[0][wo0]); gld16(Qh + g1, &Qhs[0][wo1]);
    gld16(Ql + g0, &Qls[0][wo0]); gld16(Ql + g1, &Qls[0][wo1]);
    gld16(Kh + p0, &Khs[0][wo0]); gld16(Kh + p1, &Khs[0][wo1]);
    gld16(Kl + p0, &Kls[0][wo0]); gld16(Kl + p1, &Kls[0][wo1]);
    __syncthreads();

    for (int t = 0; t < 16; ++t) {
        if (t + 1 < 16) {   // prefetch next K-step into the other buffer
            const int k0 = (t + 1) << 5;
            const int nb2 = (t + 1) & 1;
            gld16(Qh + g0 + k0, &Qhs[nb2][wo0]); gld16(Qh + g1 + k0, &Qhs[nb2][wo1]);
            gld16(Ql + g0 + k0, &Qls[nb2][wo0]); gld16(Ql + g1 + k0, &Qls[nb2][wo1]);
            gld16(Kh + p0 + k0, &Khs[nb2][wo0]); gld16(Kh + p1 + k0, &Khs[nb2][wo1]);
            gld16(Kl + p0 + k0, &Kls[nb2][wo0]); gld16(Kl + p1 + k0, &Kls[nb2][wo1]);
        }
        const int cb = t & 1;
        bf16x8 ah[8], bh[4];
#pragma unroll
        for (int i = 0; i < 8; ++i)
            ah[i] = *(const bf16x8*)&Qhs[cb][(wm + i * 16 + la) * 32 + ((h4 ^ sw) << 3)];
#pragma unroll
        for (int i = 0; i < 4; ++i)
            bh[i] = *(const bf16x8*)&Khs[cb][(wn + i * 16 + la) * 32 + ((h4 ^ sw) << 3)];
#pragma unroll
        for (int mi = 0; mi < 8; ++mi)
#pragma unroll
            for (int ni = 0; ni < 4; ++ni)
                acc[mi][ni] = __builtin_amdgcn_mfma_f32_16x16x32_bf16(ah[mi], bh[ni], acc[mi][ni], 0, 0, 0);
        {   // hi x lo
            bf16x8 bl[4];
#pragma unroll
            for (int i = 0; i < 4; ++i)
                bl[i] = *(const bf16x8*)&Kls[cb][(wn + i * 16 + la) * 32 + ((h4 ^ sw) << 3)];
#pragma unroll
            for (int mi = 0; mi < 8; ++mi)
#pragma unroll
                for (int ni = 0; ni < 4; ++ni)
                    acc[mi][ni] = __builtin_amdgcn_mfma_f32_16x16x32_bf16(ah[mi], bl[ni], acc[mi][ni], 0, 0, 0);
        }
        {   // lo x hi
            bf16x8 al[8];
#pragma unroll
            for (int i = 0; i < 8; ++i)
                al[i] = *(const bf16x8*)&Qls[cb][(wm + i * 16 + la) * 32 + ((h4 ^ sw) << 3)];
#pragma unroll
            for (int mi = 0; mi < 8; ++mi)
#pragma unroll
                for (int ni = 0; ni < 4; ++ni)
                    acc[mi][ni] = __builtin_amdgcn_mfma_f32_16x16x32_bf16(al[mi], bh[ni], acc[mi][ni], 0, 0, 0);
        }
        __syncthreads();   // drains prefetch (had full compute phase to land)
    }

    // fold accs into per-thread diagonal bins
    float rbin[11][4] = {};
#pragma unroll
    for (int mi = 0; mi < 8; ++mi)
#pragma unroll
        for (int ni = 0; ni < 4; ++ni)
#pragma unroll
            for (int r = 0; r < 4; ++r)
                rbin[mi - ni + 3][r] += acc[mi][ni][r];

    const int base = (wm - wn) + 4 * h4 - la + 255;
#pragma unroll
    for (int d = 0; d < 11; ++d)
#pragma unroll
        for (int r = 0; r < 4; ++r)
            atomicAdd(&diagw[wave][base + 16 * (d - 3) + r], rbin[d][r]);
    __syncthreads();
    if (tid < 511) {
        float s = 0.f;
#pragma unroll
        for (int w = 0; w < 8; ++w) s += diagw[w][tid];
        int n = (bt - bs + tid - 255) & 1023;
        atomicAdd(&G[(b << 10) + n], s);
    }
}

// ---------------------------------------------------------------------------
// Per-batch top-20 + softmax, parallel argmax (tie -> lowest index).
// ---------------------------------------------------------------------------
__global__ __launch_bounds__(256)
void topk_kernel(const float* __restrict__ G, int* __restrict__ delay,
                 float* __restrict__ tc)
{
    __shared__ float vals[1024];
    __shared__ float pw[4];
    __shared__ int   pwi[4];
    __shared__ float wsel[TOPK_];
    __shared__ int   isel[TOPK_];
    const int b = blockIdx.x, tid = threadIdx.x;
    const int lane = tid & 63, wid = tid >> 6;
    for (int i = tid; i < 1024; i += 256) vals[i] = G[(b << 10) + i] * (1.0f / 512.0f);
    __syncthreads();
    for (int it = 0; it < TOPK_; ++it) {
        float bv = -INFINITY; int bi = 0;
#pragma unroll
        for (int u = 0; u < 4; ++u) {
            int i = tid * 4 + u;
            float v = vals[i];
            if (v > bv) { bv = v; bi = i; }
        }
#pragma unroll
        for (int o = 32; o > 0; o >>= 1) {
            float ov = __shfl_xor(bv, o, 64);
            int   oi = __shfl_xor(bi, o, 64);
            if (ov > bv || (ov == bv && oi < bi)) { bv = ov; bi = oi; }
        }
        if (lane == 0) { pw[wid] = bv; pwi[wid] = bi; }
        __syncthreads();
        if (tid == 0) {
            float m = pw[0]; int mi = pwi[0];
#pragma unroll
            for (int t = 1; t < 4; ++t)
                if (pw[t] > m || (pw[t] == m && pwi[t] < mi)) { m = pw[t]; mi = pwi[t]; }
            wsel[it] = m; isel[it] = mi;
            vals[mi] = -INFINITY;
        }
        __syncthreads();
    }
    if (tid == 0) {
        float m = wsel[0];
#pragma unroll
        for (int i = 1; i < TOPK_; ++i) m = fmaxf(m, wsel[i]);
        float e[TOPK_], s = 0.f;
#pragma unroll
        for (int i = 0; i < TOPK_; ++i) { e[i] = expf(wsel[i] - m); s += e[i]; }
        float inv = 1.0f / s;
#pragma unroll
        for (int i = 0; i < TOPK_; ++i) {
            tc[b * TOPK_ + i] = e[i] * inv;
            delay[b * TOPK_ + i] = isel[i];
        }
    }
}

// out[b,l,d] = sum_i tc[b,i] * V[b,(l+delay)%1024,d], bf16 in/out, 8-wide.
// delay/tc hoisted to LDS once per block; XCD batch-clustering swizzle.
__global__ __launch_bounds__(256)
void agg_kernel(const unsigned short* __restrict__ V, const int* __restrict__ delay,
                const float* __restrict__ tc, unsigned short* __restrict__ out)
{
    __shared__ int   dls[TOPK_];
    __shared__ float tcs[TOPK_];
    int h = blockIdx.x, g = gridDim.x, lh = h;
    if ((g & 7) == 0) {
        int q = g >> 3;
        lh = (h & 7) * q + (h >> 3);
    }
    int idx = (lh * blockDim.x + threadIdx.x) * 8;
    int d = idx & 511;
    int l = (idx >> 9) & 1023;
    int b = idx >> 19;
    if (threadIdx.x < TOPK_) {
        dls[threadIdx.x] = delay[b * TOPK_ + threadIdx.x];
        tcs[threadIdx.x] = tc[b * TOPK_ + threadIdx.x];
    }
    __syncthreads();
    const unsigned short* Vb = V + ((size_t)b << 19);
    float s[8] = {};
#pragma unroll
    for (int i = 0; i < TOPK_; ++i) {
        int row = (l + dls[i]) & 1023;
        float w = tcs[i];
        u16x8 v = *(const u16x8*)&Vb[((size_t)row << 9) + d];
#pragma unroll
        for (int j = 0; j < 8; ++j)
            s[j] = fmaf(w, bf2f(v[j]), s[j]);
    }
    u16x8 o;
#pragma unroll
    for (int j = 0; j < 8; ++j) o[j] = f2bf(s[j]);
    *(u16x8*)&out[idx] = o;
}

// ---------------------------------------------------------------------------
// series_decomp with optional bf16 dual-out of the seasonal part.
// XCD swizzle clusters each batch's blocks on one XCD. Bit-identical.
// ---------------------------------------------------------------------------
__global__ void decomp_kernel(const float* __restrict__ x, float* __restrict__ seas,
                              unsigned short* __restrict__ seasb,
                              float* __restrict__ trend, int Bn, int Ln, int Ch,
                              int nseg, int tmode)
{
    int h = blockIdx.x, g = gridDim.x, lh = h;
    if ((g & 7) == 0) {
        int q = g >> 3;
        lh = (h & 7) * q + (h >> 3);
    }
    int idx = lh * blockDim.x + threadIdx.x;
    int total = Bn * Ch * nseg;
    if (idx >= total) return;
    int ch = idx % Ch;
    int rest = idx / Ch;
    int seg = rest % nseg;
    int b = rest / nseg;
    int segL = Ln / nseg;
    int l0 = seg * segL;
    const float* xp = x + (size_t)b * Ln * Ch + ch;
    float* sp = seas + (size_t)b * Ln * Ch + ch;
    unsigned short* bp = seasb ? seasb + (size_t)b * Ln * Ch + ch : nullptr;
    float* tp = trend ? trend + (size_t)b * Ln * Ch + ch : nullptr;
    float s = 0.f;
    for (int j = -12; j <= 12; ++j) {
        int t = l0 + j;
        t = t < 0 ? 0 : (t > Ln - 1 ? Ln - 1 : t);
        s += xp[(size_t)t * Ch];
    }
    for (int l = l0; l < l0 + segL; ++l) {
        float mm = s * (1.0f / 25.0f);
        float v = xp[(size_t)l * Ch] - mm;
        sp[(size_t)l * Ch] = v;
        if (bp) bp[(size_t)l * Ch] = f2bf(v);
        if (tmode == 1) tp[(size_t)l * Ch] = mm;
        else if (tmode == 2) tp[(size_t)l * Ch] += mm;
        int ta = l + 13; if (ta > Ln - 1) ta = Ln - 1;
        int ts = l - 12; if (ts < 0) ts = 0;
        s += xp[(size_t)ta * Ch] - xp[(size_t)ts * Ch];
    }
}

__global__ __launch_bounds__(256)
void lnrow_kernel(const float* __restrict__ x, const float* __restrict__ g,
                  const float* __restrict__ bv, float* __restrict__ out)
{
    __shared__ float sh1[4], sh2[4];
    int row = blockIdx.x, tid = threadIdx.x;
    const float* xr = x + ((size_t)row << 9);
    float v0 = xr[tid], v1 = xr[tid + 256];
    float s = v0 + v1, q = v0 * v0 + v1 * v1;
#pragma unroll
    for (int o = 32; o > 0; o >>= 1) {
        s += __shfl_down(s, o, 64);
        q += __shfl_down(q, o, 64);
    }
    int wid = tid >> 6;
    if ((tid & 63) == 0) { sh1[wid] = s; sh2[wid] = q; }
    __syncthreads();
    if (tid == 0) {
        sh1[0] = sh1[0] + sh1[1] + sh1[2] + sh1[3];
        sh2[0] = sh2[0] + sh2[1] + sh2[2] + sh2[3];
    }
    __syncthreads();
    float mu = sh1[0] * (1.0f / 512.0f);
    float var = sh2[0] * (1.0f / 512.0f) - mu * mu;
    float inv = rsqrtf(var + 1e-5f);
    out[((size_t)row << 9) + tid] = (v0 - mu) * inv * g[tid] + bv[tid];
    out[((size_t)row << 9) + tid + 256] = (v1 - mu) * inv * g[tid + 256] + bv[tid + 256];
}

__global__ void colmean_kernel(const float* __restrict__ x, float* __restrict__ m)
{
    int idx = blockIdx.x * blockDim.x + threadIdx.x;
    if (idx >= B_ * D_) return;
    int b = idx >> 9, d = idx & 511;
    const float* xp = x + ((size_t)b << 19) + d;
    float s = 0.f;
    for (int l = 0; l < L_; ++l) s += xp[(size_t)l << 9];
    m[idx] = s * (1.0f / 1024.0f);
}

// out_bf16 = x - colmean (encoder output, bf16 only)
__global__ void colsub_kernel(const float* __restrict__ x, const float* __restrict__ m,
                              unsigned short* __restrict__ out)
{
    int idx = blockIdx.x * blockDim.x + threadIdx.x;
    int d = idx & 511;
    int b = idx >> 19;
    out[idx] = f2bf(x[idx] - m[(b << 9) + d]);
}

__global__ void meanx_kernel(const float* __restrict__ x, float* __restrict__ m)
{
    int idx = blockIdx.x * blockDim.x + threadIdx.x;
    if (idx >= B_ * C_) return;
    int b = idx >> 6, c = idx & 63;
    const float* xp = x + (size_t)b * L_ * C_ + c;
    float s = 0.f;
    for (int l = 0; l < L_; ++l) s += xp[(size_t)l << 6];
    m[idx] = s * (1.0f / 1024.0f);
}

// build decoder seasonal input only (trend tail == meanc, consumed directly)
__global__ void builddec_kernel(const float* __restrict__ seenc, float* __restrict__ seasin)
{
    int idx = blockIdx.x * blockDim.x + threadIdx.x;
    int c = idx & 63;
    int l = (idx >> 6) & 1023;
    int b = idx >> 16;
    if (l < 512) {
        int src = (b << 16) + ((512 + l) << 6) + c;
        seasin[idx] = seenc[src];
    } else {
        seasin[idx] = 0.f;
    }
}

// ---------------------------------------------------------------------------
extern "C" void kernel_launch(void* const* d_in, const int* in_sizes, int n_in,
                              void* d_out, int out_size, void* d_ws, size_t ws_size,
                              hipStream_t stream)
{
    auto F = [&](int i) { return (const float*)d_in[i]; };
    const float* x_enc     = F(0);
    const float* enc_emb_w = F(2);
    const float* dec_emb_w = F(3);
    const float* enc_Wq = F(4);  const float* enc_bq = F(5);
    const float* dsa_Wq = F(6);  const float* dsa_bq = F(7);
    const float* dca_Wq = F(8);  const float* dca_bq = F(9);
    const float* enc_Wk = F(10); const float* enc_bk = F(11);
    const float* dsa_Wk = F(12); const float* dsa_bk = F(13);
    const float* dca_Wk = F(14); const float* dca_bk = F(15);
    const float* enc_Wv = F(16); const float* enc_bv = F(17);
    const float* dsa_Wv = F(18); const float* dsa_bv = F(19);
    const float* dca_Wv = F(20); const float* dca_bv = F(21);
    const float* enc_Wo = F(22); const float* enc_bo = F(23);
    const float* dsa_Wo = F(24); const float* dsa_bo = F(25);
    const float* dca_Wo = F(26); const float* dca_bo = F(27);
    const float* enc_ff1 = F(28); const float* enc_ff2 = F(29);
    const float* enc_ng = F(30);  const float* enc_nb = F(31);
    const float* dec_ff1 = F(32); const float* dec_ff2 = F(33);
    const float* dec_trend_w = F(34);
    const float* proj_w = F(35);  const float* proj_b = F(36);

    constexpr size_t F512 = (size_t)B_ * L_ * D_;   // 8388608
    constexpr size_t F64  = (size_t)B_ * L_ * C_;   // 1048576
    constexpr size_t SMALL = 1024 + 16384 + 320 + 320 + 8192;
    constexpr size_t WTSA_N = 16 * 262144;          // persistent attn weights (bf16)
    constexpr size_t WTSF_N = 2 * 1024 * 1024;      // ff weight scratch (bf16)
    size_t need = (3 * F512 + 2 * F64 + SMALL) * 4 + (8 * F512 + WTSA_N + WTSF_N) * 2;
    if (ws_size < need) return;

    float* X      = (float*)d_ws;
    float* T1     = X + F512;
    float* TSUM   = T1 + F512;
    float* SEASIN = TSUM + F512;
    float* PET    = SEASIN + F64;   // posemb table (524288 floats, slab is F64)
    float* MEANC  = PET + F64;
    float* G      = MEANC + 1024;
    float* TCW    = G + 16384;
    int*   DEL    = (int*)(TCW + 320);
    float* LNMEAN = (float*)(DEL + 320);
    unsigned short* AB   = (unsigned short*)(LNMEAN + 8192);
    unsigned short* EB   = AB + F512;
    unsigned short* VB   = EB + F512;
    unsigned short* HB   = VB + F512;
    unsigned short* QHI  = HB + F512;
    unsigned short* QLO  = QHI + F512;
    unsigned short* KHI  = QLO + F512;
    unsigned short* KLO  = KHI + F512;
    unsigned short* WTSA = KLO + F512;
    unsigned short* WTSF = WTSA + WTSA_N;
    float* OUT = (float*)d_out;

    const int M = B_ * L_;  // 16384

    auto mgemm = [&](const unsigned short* A, const unsigned short* Bt, float* Cf,
                     unsigned short* Cb, unsigned short* Cl, const float* bias,
                     int Mm, int Nn, int Kk, int flags) {
        int nx = Nn / 128;
        int total = nx * (Mm / 128);
        gemm_bf16<<<total, 256, 0, stream>>>(A, Bt, Cf, Cb, Cl, bias, Mm, Nn, Kk, flags, nx);
    };
    auto tcast = [&](const float* W, unsigned short* Wt, int R, int Cc) {
        tcast_kernel<<<dim3(Cc / 32, R / 32), 256, 0, stream>>>(W, Wt, R, Cc);
    };
    auto corr_topk_agg = [&]() {
        corr_mfma<<<256, 512, 0, stream>>>(QHI, QLO, KHI, KLO, G);
        topk_kernel<<<16, 256, 0, stream>>>(G, DEL, TCW);
        agg_kernel<<<(int)(F512 / 8 / 256), 256, 0, stream>>>(VB, DEL, TCW, HB);
    };
    // self-attn: Q,K,V in one merged GEMM (weight slots contiguous); zeroes G
    auto attn_self = [&](const unsigned short* xin, int slotbase,
                         const float* bq, const float* bk, const float* bvp, const float* bo,
                         float* resid) {
        gemm_split<<<12 * 128, 256, 0, stream>>>(xin, WTSA + (size_t)slotbase * 262144,
            QHI, QLO, bq, KHI, KLO, bk, VB, nullptr, bvp, G, M, 1536, 512, 12);
        corr_topk_agg();
        mgemm(HB, WTSA + (size_t)(slotbase + 3) * 262144, resid, nullptr, nullptr, bo, M, 512, 512, 1);
    };
    // cross-attn: Q separate (different input); K,V merged (zeroes G)
    auto attn_cross = [&](const unsigned short* qin, const unsigned short* kvin, int slotbase,
                          const float* bq, const float* bk, const float* bvp, const float* bo,
                          float* resid) {
        mgemm(qin, WTSA + (size_t)slotbase * 262144, nullptr, QHI, QLO, bq, M, 512, 512, 0);
        gemm_split<<<8 * 128, 256, 0, stream>>>(kvin, WTSA + (size_t)(slotbase + 1) * 262144,
            KHI, KLO, bk, VB, nullptr, bvp, nullptr, nullptr, nullptr, G, M, 1024, 512, 8);
        corr_topk_agg();
        mgemm(HB, WTSA + (size_t)(slotbase + 3) * 262144, resid, nullptr, nullptr, bo, M, 512, 512, 1);
    };
    auto ffblock = [&](const unsigned short* xin, const float* W1, const float* W2, float* resid) {
        unsigned short* Wf1 = WTSF;
        unsigned short* Wf2 = WTSF + 1048576;
        unsigned short* HFULL = QHI;   // spans QHI..KLO exactly (4*F512 elems)
        tcast(W1, Wf1, 512, 2048);
        tcast(W2, Wf2, 2048, 512);
        gemm256_gelu<<<512, 512, 0, stream>>>(xin, Wf1, HFULL, M, 2048, 512, 8);
        mgemm(HFULL, Wf2, resid, nullptr, nullptr, nullptr, M, 512, 2048, 1);
    };

    // ---------------- upfront: batched attn weight transpose + PE table -----
    {
        P16 srcs;
        for (int l = 0; l < 2; ++l) {
            srcs.p[l * 4 + 0] = enc_Wq + (size_t)l * 262144;
            srcs.p[l * 4 + 1] = enc_Wk + (size_t)l * 262144;
            srcs.p[l * 4 + 2] = enc_Wv + (size_t)l * 262144;
            srcs.p[l * 4 + 3] = enc_Wo + (size_t)l * 262144;
        }
        srcs.p[8]  = dsa_Wq; srcs.p[9]  = dsa_Wk; srcs.p[10] = dsa_Wv; srcs.p[11] = dsa_Wo;
        srcs.p[12] = dca_Wq; srcs.p[13] = dca_Wk; srcs.p[14] = dca_Wv; srcs.p[15] = dca_Wo;
        tcast_all<<<dim3(16, 16, 16), 256, 0, stream>>>(srcs, WTSA);
    }
    pegen_kernel<<<2048, 256, 0, stream>>>(PET);

    // ---------------- prep: decomposition of x_enc, decoder inits -----------
    float* SEENC = (float*)QHI;   // alias: prep phase only
    decomp_kernel<<<(B_ * C_ * 64 + 255) / 256, 256, 0, stream>>>(x_enc, SEENC, nullptr, nullptr, B_, L_, C_, 64, 0);
    meanx_kernel<<<(B_ * C_ + 255) / 256, 256, 0, stream>>>(x_enc, MEANC);
    builddec_kernel<<<(int)(F64 / 256), 256, 0, stream>>>(SEENC, SEASIN);

    // ---------------- encoder ----------------------------------------------
    emb_kernel<<<dim3(8, 256), 256, 0, stream>>>(x_enc, enc_emb_w, PET, X, AB);

    for (int l = 0; l < 2; ++l) {
        attn_self(AB, l * 4,
                  enc_bq + l * D_, enc_bk + l * D_, enc_bv + l * D_, enc_bo + l * D_, X);
        decomp_kernel<<<(B_ * D_ * 64 + 255) / 256, 256, 0, stream>>>(X, T1, AB, nullptr, B_, L_, D_, 64, 0);
        ffblock(AB, enc_ff1 + (size_t)l * D_ * DFF_, enc_ff2 + (size_t)l * DFF_ * D_, T1);
        decomp_kernel<<<(B_ * D_ * 64 + 255) / 256, 256, 0, stream>>>(T1, X, AB, nullptr, B_, L_, D_, 64, 0);
    }
    lnrow_kernel<<<M, 256, 0, stream>>>(X, enc_ng, enc_nb, T1);
    colmean_kernel<<<(B_ * D_ + 255) / 256, 256, 0, stream>>>(T1, LNMEAN);
    colsub_kernel<<<(int)(F512 / 256), 256, 0, stream>>>(T1, LNMEAN, EB);

    // ---------------- decoder ----------------------------------------------
    float* XD = X;
    emb_kernel<<<dim3(8, 256), 256, 0, stream>>>(SEASIN, dec_emb_w, PET, XD, AB);

    attn_self(AB, 8, dsa_bq, dsa_bk, dsa_bv, dsa_bo, XD);
    decomp_kernel<<<(B_ * D_ * 64 + 255) / 256, 256, 0, stream>>>(XD, T1, AB, TSUM, B_, L_, D_, 64, 1);

    attn_cross(AB, EB, 12, dca_bq, dca_bk, dca_bv, dca_bo, T1);
    decomp_kernel<<<(B_ * D_ * 64 + 255) / 256, 256, 0, stream>>>(T1, XD, AB, TSUM, B_, L_, D_, 64, 2);

    ffblock(AB, dec_ff1, dec_ff2, XD);
    decomp_kernel<<<(B_ * D_ * 64 + 255) / 256, 256, 0, stream>>>(XD, T1, nullptr, TSUM, B_, L_, D_, 64, 2);

    // fused trend-conv + proj, K-split x8 into partials, then deterministic reduce
    float* PART_C = (float*)QHI;                       // dead slab
    float* PART_P = PART_C + (size_t)8 * 8192 * 64;
    tail_kernel<<<dim3(512, 8), 256, 0, stream>>>(TSUM, T1, dec_trend_w, proj_w, PART_C, PART_P);
    tailred_kernel<<<2048, 256, 0, stream>>>(PART_C, PART_P, MEANC, proj_b, OUT);
}